// Round 2
// baseline (835.557 us; speedup 1.0000x reference)
//
#include <hip/hip_runtime.h>
#include <math.h>

#define HDIM 2048
#define WDIM 2048
#define NPIX (HDIM*WDIM)
#define OUTW 2038          /* valid conv output size: 2048-10 */

#define C1F 6.5025f        /* (0.01*255)^2 */
#define C2F 58.5225f       /* (0.03*255)^2 */

constexpr int TH  = 64, TW = 32;   // output tile
constexpr int IH  = TH + 10;       // 74 input rows
constexpr int IWD = 11;            // dwords per LDS input row (44 cols, 42 used)
constexpr int HS  = 36;            // h-array row stride in halves (72 B, odd granule)
constexpr int NBLK = 8192;         // 64 x 32 x 4

struct GaussW { float g[11]; };

typedef _Float16 h4_t __attribute__((ext_vector_type(4)));

// Quantization exactly mirroring the reference _to_uint8_float op sequence (f32).
__device__ __forceinline__ float quant_u8(float x) {
    float xc  = fminf(fmaxf(x, -1.0f), 1.0f);
    float x01 = (xc + 1.0f) * 0.5f;
    x01 = fminf(fmaxf(x01, 0.0f), 1.0f);
    float v = x01 * 255.0f;
    v = fminf(fmaxf(v, 0.0f), 255.0f);
    return floorf(v);
}

// ---------------------------------------------------------------------------
// Fused kernel: per 64x32 tile
//   stage A: load f32, pointwise stats on owned core, quantize+pack u8x4 -> LDS
//   stage B: horizontal 11-tap conv of {p,t,p2,t2,pt} -> f16 LDS (+ u8 SSE stat)
//   stage C: vertical 11-tap + SSIM map
//   partials: pr[c*8192 + bid], c = 0:l1 1:gxH 2:gyW 3:relu 4:sp 5:st
//             6:spp 7:stt 8:su8 9:ssim
// ---------------------------------------------------------------------------
__global__ __launch_bounds__(256, 4) void amsr2_fused(
        const float* __restrict__ pred, const float* __restrict__ targ,
        float* __restrict__ pr, GaussW gw)
{
    __shared__ unsigned sp[IH * IWD];
    __shared__ unsigned st[IH * IWD];
    __shared__ alignas(16) _Float16 hp [IH*HS];
    __shared__ alignas(16) _Float16 ht [IH*HS];
    __shared__ alignas(16) _Float16 hpp[IH*HS];
    __shared__ alignas(16) _Float16 htt[IH*HS];
    __shared__ alignas(16) _Float16 hpt[IH*HS];
    __shared__ float sred[4][10];

    float G[11];
#pragma unroll
    for (int i = 0; i < 11; ++i) G[i] = gw.g[i];

    const int b  = blockIdx.z;
    const int r0 = blockIdx.y * TH;
    const int c0 = blockIdx.x * TW;
    const float* pb = pred + (size_t)b * NPIX;
    const float* tb = targ + (size_t)b * NPIX;

    float s[9];
#pragma unroll
    for (int c = 0; c < 9; ++c) s[c] = 0.0f;

    // ---- stage A: load + stats (core) + quantize/pack into LDS ----
    for (int item = threadIdx.x; item < IH * IWD; item += 256) {
        int r = item / IWD, d = item - r * IWD;
        int gr = r0 + r, gc = c0 + d * 4;
        float pv[4], tv[4];
        bool vec = (gr < HDIM) && (gc + 3 < WDIM);
        if (vec) {
            const float* prow = pb + (size_t)gr * WDIM + gc;
            const float* trow = tb + (size_t)gr * WDIM + gc;
            float4 a4 = *(const float4*)prow;
            float4 b4 = *(const float4*)trow;
            pv[0]=a4.x; pv[1]=a4.y; pv[2]=a4.z; pv[3]=a4.w;
            tv[0]=b4.x; tv[1]=b4.y; tv[2]=b4.z; tv[3]=b4.w;
            if (r < TH && d < 8) {               // owned core pixels: stats
                bool down = (gr + 1 < HDIM);
                float pd[4] = {0,0,0,0}, td[4] = {0,0,0,0};
                if (down) {
                    float4 a4d = *(const float4*)(prow + WDIM);
                    float4 b4d = *(const float4*)(trow + WDIM);
                    pd[0]=a4d.x; pd[1]=a4d.y; pd[2]=a4d.z; pd[3]=a4d.w;
                    td[0]=b4d.x; td[1]=b4d.y; td[2]=b4d.z; td[3]=b4d.w;
                }
                bool hasR = (gc + 4 < WDIM);
                float p5 = hasR ? prow[4] : 0.0f;
                float t5 = hasR ? trow[4] : 0.0f;
#pragma unroll
                for (int k = 0; k < 4; ++k) {
                    float av = pv[k], bv = tv[k];
                    float dd = av - bv;
                    s[0] += fabsf(dd);
                    s[3] += fmaxf(fabsf(av) - 1.0f, 0.0f);
                    s[4] += av;  s[5] += bv;
                    s[6] += av * av;  s[7] += bv * bv;
                    if (down) {                     // gradient along H
                        float dn = pd[k] - td[k];
                        s[1] += fabsf(dd - dn);
                    }
                    float nr  = (k < 3) ? pv[k+1] : p5;
                    float nrt = (k < 3) ? tv[k+1] : t5;
                    if (k < 3 || hasR) {            // gradient along W
                        s[2] += fabsf(dd - (nr - nrt));
                    }
                }
            }
        } else {
            const float* prow = pb + (size_t)gr * WDIM;
            const float* trow = tb + (size_t)gr * WDIM;
#pragma unroll
            for (int k = 0; k < 4; ++k) {
                int gcc = gc + k;
                bool ok = (gr < HDIM) && (gcc < WDIM);
                pv[k] = ok ? prow[gcc] : 0.0f;
                tv[k] = ok ? trow[gcc] : 0.0f;
            }
        }
        unsigned up = 0u, ut = 0u;
#pragma unroll
        for (int k = 0; k < 4; ++k) {
            up |= ((unsigned)(int)quant_u8(pv[k])) << (8*k);
            ut |= ((unsigned)(int)quant_u8(tv[k])) << (8*k);
        }
        sp[item] = up; st[item] = ut;
    }
    __syncthreads();

    // ---- stage B: horizontal conv -> f16 LDS; fold in u8 SSE stat ----
    for (int item = threadIdx.x; item < IH * 8; item += 256) {
        int r = item >> 3, c4 = item & 7;
        int bs = r * IWD + c4;
        unsigned ap[4] = {sp[bs], sp[bs+1], sp[bs+2], sp[bs+3]};
        unsigned at[4] = {st[bs], st[bs+1], st[bs+2], st[bs+3]};
        float aA[4]={0,0,0,0}, aB[4]={0,0,0,0};
        float aPP[4]={0,0,0,0}, aTT[4]={0,0,0,0}, aPT[4]={0,0,0,0};
        bool core_r = (r < TH);
#pragma unroll
        for (int i = 0; i < 14; ++i) {
            float a = (float)((ap[i>>2] >> ((i&3)*8)) & 0xffu);
            float c = (float)((at[i>>2] >> ((i&3)*8)) & 0xffu);
            float pp = a*a, tt = c*c, pt = a*c;
            if (i < 4 && core_r) {       // each core pixel exactly once
                float qd = a - c;
                s[8] += qd * qd;
            }
#pragma unroll
            for (int o = 0; o < 4; ++o) {
                int j = i - o;
                if (j >= 0 && j <= 10) {
                    float gj = G[j];
                    aA[o]  += gj * a;   aB[o]  += gj * c;
                    aPP[o] += gj * pp;  aTT[o] += gj * tt;  aPT[o] += gj * pt;
                }
            }
        }
        int hb = r * HS + c4 * 4;
        h4_t vA, vB, vPP, vTT, vPT;
#pragma unroll
        for (int k = 0; k < 4; ++k) {
            vA[k]  = (_Float16)aA[k];   vB[k]  = (_Float16)aB[k];
            vPP[k] = (_Float16)aPP[k];  vTT[k] = (_Float16)aTT[k];
            vPT[k] = (_Float16)aPT[k];
        }
        *(h4_t*)&hp [hb] = vA;  *(h4_t*)&ht [hb] = vB;
        *(h4_t*)&hpp[hb] = vPP; *(h4_t*)&htt[hb] = vTT;
        *(h4_t*)&hpt[hb] = vPT;
    }
    __syncthreads();

    // ---- stage C: vertical conv + SSIM map; 2 rows x 4 cols per thread ----
    float ssum = 0.0f;
    {
        int oy0 = (threadIdx.x >> 3) * 2;
        int ox0 = (threadIdx.x & 7) * 4;
        float acc[2][5][4] = {};
#pragma unroll
        for (int j = 0; j < 12; ++j) {
            int hb = (oy0 + j) * HS + ox0;
            h4_t q0 = *(const h4_t*)&hp [hb];
            h4_t q1 = *(const h4_t*)&ht [hb];
            h4_t q2 = *(const h4_t*)&hpp[hb];
            h4_t q3 = *(const h4_t*)&htt[hb];
            h4_t q4 = *(const h4_t*)&hpt[hb];
            float f[5][4];
#pragma unroll
            for (int k = 0; k < 4; ++k) {
                f[0][k] = (float)q0[k]; f[1][k] = (float)q1[k];
                f[2][k] = (float)q2[k]; f[3][k] = (float)q3[k];
                f[4][k] = (float)q4[k];
            }
            if (j < 11) {
                float gj = G[j];
#pragma unroll
                for (int a = 0; a < 5; ++a)
#pragma unroll
                    for (int k = 0; k < 4; ++k) acc[0][a][k] += gj * f[a][k];
            }
            if (j >= 1) {
                float gj = G[j-1];
#pragma unroll
                for (int a = 0; a < 5; ++a)
#pragma unroll
                    for (int k = 0; k < 4; ++k) acc[1][a][k] += gj * f[a][k];
            }
        }
        int th_ = min(TH, OUTW - r0);
        int tw_ = min(TW, OUTW - c0);
#pragma unroll
        for (int rr = 0; rr < 2; ++rr) {
            if (oy0 + rr < th_) {
#pragma unroll
                for (int k = 0; k < 4; ++k) {
                    if (ox0 + k < tw_) {
                        float mu1 = acc[rr][0][k], mu2 = acc[rr][1][k];
                        float vpp = acc[rr][2][k], vtt = acc[rr][3][k], vpt = acc[rr][4][k];
                        float mu1s = mu1*mu1, mu2s = mu2*mu2, mu12 = mu1*mu2;
                        float sg1 = vpp - mu1s, sg2 = vtt - mu2s, sg12 = vpt - mu12;
                        float num = (2.0f*mu12 + C1F) * (2.0f*sg12 + C2F);
                        float den = (mu1s + mu2s + C1F) * (sg1 + sg2 + C2F);
                        ssum += num / den;
                    }
                }
            }
        }
    }

    // ---- block reduction of 10 partials ----
    float st10[10];
#pragma unroll
    for (int c = 0; c < 9; ++c) st10[c] = s[c];
    st10[9] = ssum;
#pragma unroll
    for (int c = 0; c < 10; ++c) {
        float v = st10[c];
        for (int off = 32; off > 0; off >>= 1) v += __shfl_down(v, off);
        st10[c] = v;
    }
    int lane = threadIdx.x & 63, wid = threadIdx.x >> 6;
    if (lane == 0) {
#pragma unroll
        for (int c = 0; c < 10; ++c) sred[wid][c] = st10[c];
    }
    __syncthreads();
    if (threadIdx.x < 10) {
        int c = threadIdx.x;
        int bid = ((blockIdx.z * 32) + blockIdx.y) * 64 + blockIdx.x;
        pr[c * NBLK + bid] = sred[0][c] + sred[1][c] + sred[2][c] + sred[3][c];
    }
}

// ---------------------------------------------------------------------------
// Final combine: 28 segments reduced wave-parallel in f64.
// ---------------------------------------------------------------------------
__global__ __launch_bounds__(256) void amsr2_final(
        const float* __restrict__ pr, float* __restrict__ out)
{
    __shared__ double res[28];
    int wid = threadIdx.x >> 6, lane = threadIdx.x & 63;
    for (int c = wid; c < 28; c += 4) {
        const float* base; int n;
        if (c < 4)       { base = pr + c * NBLK; n = NBLK; }
        else if (c < 24) { int cc = c - 4; int s_ = 4 + (cc >> 2); int b_ = cc & 3;
                           base = pr + s_ * NBLK + b_ * 2048; n = 2048; }
        else             { int b_ = c - 24; base = pr + 9 * NBLK + b_ * 2048; n = 2048; }
        double sacc = 0.0;
        for (int i = lane; i < n; i += 64) sacc += (double)base[i];
        for (int off = 32; off > 0; off >>= 1) sacc += __shfl_down(sacc, off);
        if (lane == 0) res[c] = sacc;
    }
    __syncthreads();
    if (threadIdx.x == 0) {
        const double n = (double)NPIX;
        double l1   = res[0] / (4.0 * n);
        double grad = res[1] / (4.0 * 2047.0 * 2048.0) + res[2] / (4.0 * 2048.0 * 2047.0);
        double energy = 0.0, dist = 0.0, psnr_sum = 0.0, ssim_sum = 0.0;
        for (int b = 0; b < 4; ++b) {
            double Sp  = res[4 + b],  St  = res[8 + b];
            double Spp = res[12 + b], Stt = res[16 + b];
            double Su8 = res[20 + b], Sss = res[24 + b];
            double pm = Sp / n, tm = St / n;
            double dm = pm - tm; energy += dm * dm;
            double vp = (Spp - n * pm * pm) / (n - 1.0);
            double vt = (Stt - n * tm * tm) / (n - 1.0);
            double ps = sqrt(fmax(vp, 0.0)), ts = sqrt(fmax(vt, 0.0));
            double dd = ps - ts; dist += dd * dd;
            double mse = Su8 / n;
            double psnr = (mse == 0.0) ? 100.0 : 10.0 * log10(65025.0 / fmax(mse, 1e-12));
            psnr_sum += psnr;
            ssim_sum += Sss / ((double)OUTW * (double)OUTW);
        }
        energy *= 0.25; dist *= 0.25;
        double range_pen = res[3] / (4.0 * n);
        double phys = energy + 0.5 * dist + 0.1 * range_pen;
        double ssim_mean = fmin(fmax(ssim_sum * 0.25, 0.0), 1.0);
        double total = l1 + 0.15 * grad + 0.05 * phys + 0.1 * (1.0 - ssim_mean);
        out[0] = (float)total;
        out[1] = (float)(psnr_sum * 0.25);
        out[2] = (float)ssim_mean;
    }
}

extern "C" void kernel_launch(void* const* d_in, const int* in_sizes, int n_in,
                              void* d_out, int out_size, void* d_ws, size_t ws_size,
                              hipStream_t stream)
{
    (void)in_sizes; (void)n_in; (void)out_size; (void)ws_size;
    const float* pred = (const float*)d_in[0];
    const float* targ = (const float*)d_in[1];
    float* out = (float*)d_out;
    float* pr  = (float*)d_ws;            // 10 * 8192 floats of partials

    GaussW gw;                            // host-side f64 Gaussian, cast to f32
    {
        double e[11], sm = 0.0;
        for (int i = 0; i < 11; ++i) {
            double d = (double)(i - 5);
            e[i] = exp(-(d * d) / 4.5);
            sm += e[i];
        }
        for (int i = 0; i < 11; ++i) gw.g[i] = (float)(e[i] / sm);
    }

    amsr2_fused<<<dim3(64, 32, 4), 256, 0, stream>>>(pred, targ, pr, gw);
    amsr2_final<<<1, 256, 0, stream>>>(pr, out);
}

// Round 3
// 520.378 us; speedup vs baseline: 1.6057x; 1.6057x over previous
//
#include <hip/hip_runtime.h>
#include <math.h>

#define HDIM 2048
#define WDIM 2048
#define NPIX (HDIM*WDIM)
#define OUTW 2038          /* valid conv output size: 2048-10 */

#define C1F 6.5025f        /* (0.01*255)^2 */
#define C2F 58.5225f       /* (0.03*255)^2 */

constexpr int TH  = 64, TW = 32;   // output tile
constexpr int IH  = TH + 10;       // 74 input rows
constexpr int IWD = 11;            // dwords per LDS input row (44 cols, 42 used)
constexpr int HSH = 40;            // h-array row stride in halves = 20 dwords (== 4 mod 16:
                                   //   stage-C read banks 8*dg+2*dc mod 32 -> max 2-way, free)
constexpr int NBLK = 8192;         // 64 x 32 x 4

struct GaussW { float g[11]; };

typedef _Float16 h4_t __attribute__((ext_vector_type(4)));

// Quantization exactly mirroring the reference _to_uint8_float op sequence (f32).
__device__ __forceinline__ float quant_u8(float x) {
    float xc  = fminf(fmaxf(x, -1.0f), 1.0f);
    float x01 = (xc + 1.0f) * 0.5f;
    x01 = fminf(fmaxf(x01, 0.0f), 1.0f);
    float v = x01 * 255.0f;
    v = fminf(fmaxf(v, 0.0f), 255.0f);
    return floorf(v);
}

// ---------------------------------------------------------------------------
// Fused kernel: per 64x32 tile
//   stage A: load f32, pointwise stats on owned core, quantize+pack u8x4 -> LDS
//   stage B: horizontal 11-tap conv of {p,t,p2,t2,pt} -> f16 LDS (+ u8 SSE stat)
//   stage C: vertical 11-tap + SSIM map
//   partials: pr[c*8192 + bid], c = 0:l1 1:gxH 2:gyW 3:relu 4:sp 5:st
//             6:spp 7:stt 8:su8 9:ssim
// NOTE: plain __launch_bounds__(256). The (256,4) hint in round 2 capped the
// allocator at 64 VGPRs -> ~2.3 GB of scratch spill traffic per launch.
// ---------------------------------------------------------------------------
__global__ __launch_bounds__(256) void amsr2_fused(
        const float* __restrict__ pred, const float* __restrict__ targ,
        float* __restrict__ pr, GaussW gw)
{
    __shared__ unsigned sp[IH * IWD];
    __shared__ unsigned st[IH * IWD];
    __shared__ alignas(16) _Float16 hp [IH*HSH];
    __shared__ alignas(16) _Float16 ht [IH*HSH];
    __shared__ alignas(16) _Float16 hpp[IH*HSH];
    __shared__ alignas(16) _Float16 htt[IH*HSH];
    __shared__ alignas(16) _Float16 hpt[IH*HSH];
    __shared__ float sred[4][10];

    float G[11];
#pragma unroll
    for (int i = 0; i < 11; ++i) G[i] = gw.g[i];

    const int b  = blockIdx.z;
    const int r0 = blockIdx.y * TH;
    const int c0 = blockIdx.x * TW;
    const float* pb = pred + (size_t)b * NPIX;
    const float* tb = targ + (size_t)b * NPIX;

    float s[9];
#pragma unroll
    for (int c = 0; c < 9; ++c) s[c] = 0.0f;

    // ---- stage A: load + stats (core) + quantize/pack into LDS ----
    for (int item = threadIdx.x; item < IH * IWD; item += 256) {
        int r = item / IWD, d = item - r * IWD;
        int gr = r0 + r, gc = c0 + d * 4;
        float pv[4], tv[4];
        bool vec = (gr < HDIM) && (gc + 3 < WDIM);
        if (vec) {
            const float* prow = pb + (size_t)gr * WDIM + gc;
            const float* trow = tb + (size_t)gr * WDIM + gc;
            float4 a4 = *(const float4*)prow;
            float4 b4 = *(const float4*)trow;
            pv[0]=a4.x; pv[1]=a4.y; pv[2]=a4.z; pv[3]=a4.w;
            tv[0]=b4.x; tv[1]=b4.y; tv[2]=b4.z; tv[3]=b4.w;
            if (r < TH && d < 8) {               // owned core pixels: stats
                bool down = (gr + 1 < HDIM);
                float pd[4] = {0,0,0,0}, td[4] = {0,0,0,0};
                if (down) {
                    float4 a4d = *(const float4*)(prow + WDIM);
                    float4 b4d = *(const float4*)(trow + WDIM);
                    pd[0]=a4d.x; pd[1]=a4d.y; pd[2]=a4d.z; pd[3]=a4d.w;
                    td[0]=b4d.x; td[1]=b4d.y; td[2]=b4d.z; td[3]=b4d.w;
                }
                bool hasR = (gc + 4 < WDIM);
                float p5 = hasR ? prow[4] : 0.0f;
                float t5 = hasR ? trow[4] : 0.0f;
#pragma unroll
                for (int k = 0; k < 4; ++k) {
                    float av = pv[k], bv = tv[k];
                    float dd = av - bv;
                    s[0] += fabsf(dd);
                    s[3] += fmaxf(fabsf(av) - 1.0f, 0.0f);
                    s[4] += av;  s[5] += bv;
                    s[6] += av * av;  s[7] += bv * bv;
                    if (down) {                     // gradient along H
                        float dn = pd[k] - td[k];
                        s[1] += fabsf(dd - dn);
                    }
                    float nr  = (k < 3) ? pv[k+1] : p5;
                    float nrt = (k < 3) ? tv[k+1] : t5;
                    if (k < 3 || hasR) {            // gradient along W
                        s[2] += fabsf(dd - (nr - nrt));
                    }
                }
            }
        } else {
            const float* prow = pb + (size_t)gr * WDIM;
            const float* trow = tb + (size_t)gr * WDIM;
#pragma unroll
            for (int k = 0; k < 4; ++k) {
                int gcc = gc + k;
                bool ok = (gr < HDIM) && (gcc < WDIM);
                pv[k] = ok ? prow[gcc] : 0.0f;
                tv[k] = ok ? trow[gcc] : 0.0f;
            }
        }
        unsigned up = 0u, ut = 0u;
#pragma unroll
        for (int k = 0; k < 4; ++k) {
            up |= ((unsigned)(int)quant_u8(pv[k])) << (8*k);
            ut |= ((unsigned)(int)quant_u8(tv[k])) << (8*k);
        }
        sp[item] = up; st[item] = ut;
    }
    __syncthreads();

    // ---- stage B: horizontal conv -> f16 LDS; fold in u8 SSE stat ----
    for (int item = threadIdx.x; item < IH * 8; item += 256) {
        int r = item >> 3, c4 = item & 7;
        int bs = r * IWD + c4;
        unsigned ap[4] = {sp[bs], sp[bs+1], sp[bs+2], sp[bs+3]};
        unsigned at[4] = {st[bs], st[bs+1], st[bs+2], st[bs+3]};
        float aA[4]={0,0,0,0}, aB[4]={0,0,0,0};
        float aPP[4]={0,0,0,0}, aTT[4]={0,0,0,0}, aPT[4]={0,0,0,0};
        bool core_r = (r < TH);
#pragma unroll
        for (int i = 0; i < 14; ++i) {
            float a = (float)((ap[i>>2] >> ((i&3)*8)) & 0xffu);
            float c = (float)((at[i>>2] >> ((i&3)*8)) & 0xffu);
            float pp = a*a, tt = c*c, pt = a*c;
            if (i < 4 && core_r) {       // each core pixel exactly once
                float qd = a - c;
                s[8] += qd * qd;
            }
#pragma unroll
            for (int o = 0; o < 4; ++o) {
                int j = i - o;
                if (j >= 0 && j <= 10) {
                    float gj = G[j];
                    aA[o]  += gj * a;   aB[o]  += gj * c;
                    aPP[o] += gj * pp;  aTT[o] += gj * tt;  aPT[o] += gj * pt;
                }
            }
        }
        int hb = r * HSH + c4 * 4;
        h4_t vA, vB, vPP, vTT, vPT;
#pragma unroll
        for (int k = 0; k < 4; ++k) {
            vA[k]  = (_Float16)aA[k];   vB[k]  = (_Float16)aB[k];
            vPP[k] = (_Float16)aPP[k];  vTT[k] = (_Float16)aTT[k];
            vPT[k] = (_Float16)aPT[k];
        }
        *(h4_t*)&hp [hb] = vA;  *(h4_t*)&ht [hb] = vB;
        *(h4_t*)&hpp[hb] = vPP; *(h4_t*)&htt[hb] = vTT;
        *(h4_t*)&hpt[hb] = vPT;
    }
    __syncthreads();

    // ---- stage C: vertical conv + SSIM map; 2 rows x 4 cols per thread ----
    float ssum = 0.0f;
    {
        int oy0 = (threadIdx.x >> 3) * 2;
        int ox0 = (threadIdx.x & 7) * 4;
        float acc[2][5][4] = {};
#pragma unroll
        for (int j = 0; j < 12; ++j) {
            int hb = (oy0 + j) * HSH + ox0;
            h4_t q0 = *(const h4_t*)&hp [hb];
            h4_t q1 = *(const h4_t*)&ht [hb];
            h4_t q2 = *(const h4_t*)&hpp[hb];
            h4_t q3 = *(const h4_t*)&htt[hb];
            h4_t q4 = *(const h4_t*)&hpt[hb];
            float f[5][4];
#pragma unroll
            for (int k = 0; k < 4; ++k) {
                f[0][k] = (float)q0[k]; f[1][k] = (float)q1[k];
                f[2][k] = (float)q2[k]; f[3][k] = (float)q3[k];
                f[4][k] = (float)q4[k];
            }
            if (j < 11) {
                float gj = G[j];
#pragma unroll
                for (int a = 0; a < 5; ++a)
#pragma unroll
                    for (int k = 0; k < 4; ++k) acc[0][a][k] += gj * f[a][k];
            }
            if (j >= 1) {
                float gj = G[j-1];
#pragma unroll
                for (int a = 0; a < 5; ++a)
#pragma unroll
                    for (int k = 0; k < 4; ++k) acc[1][a][k] += gj * f[a][k];
            }
        }
        int th_ = min(TH, OUTW - r0);
        int tw_ = min(TW, OUTW - c0);
#pragma unroll
        for (int rr = 0; rr < 2; ++rr) {
            if (oy0 + rr < th_) {
#pragma unroll
                for (int k = 0; k < 4; ++k) {
                    if (ox0 + k < tw_) {
                        float mu1 = acc[rr][0][k], mu2 = acc[rr][1][k];
                        float vpp = acc[rr][2][k], vtt = acc[rr][3][k], vpt = acc[rr][4][k];
                        float mu1s = mu1*mu1, mu2s = mu2*mu2, mu12 = mu1*mu2;
                        float sg1 = vpp - mu1s, sg2 = vtt - mu2s, sg12 = vpt - mu12;
                        float num = (2.0f*mu12 + C1F) * (2.0f*sg12 + C2F);
                        float den = (mu1s + mu2s + C1F) * (sg1 + sg2 + C2F);
                        ssum += num / den;
                    }
                }
            }
        }
    }

    // ---- block reduction of 10 partials ----
    float st10[10];
#pragma unroll
    for (int c = 0; c < 9; ++c) st10[c] = s[c];
    st10[9] = ssum;
#pragma unroll
    for (int c = 0; c < 10; ++c) {
        float v = st10[c];
        for (int off = 32; off > 0; off >>= 1) v += __shfl_down(v, off);
        st10[c] = v;
    }
    int lane = threadIdx.x & 63, wid = threadIdx.x >> 6;
    if (lane == 0) {
#pragma unroll
        for (int c = 0; c < 10; ++c) sred[wid][c] = st10[c];
    }
    __syncthreads();
    if (threadIdx.x < 10) {
        int c = threadIdx.x;
        int bid = ((blockIdx.z * 32) + blockIdx.y) * 64 + blockIdx.x;
        pr[c * NBLK + bid] = sred[0][c] + sred[1][c] + sred[2][c] + sred[3][c];
    }
}

// ---------------------------------------------------------------------------
// Final combine: 28 segments reduced wave-parallel in f64.
// ---------------------------------------------------------------------------
__global__ __launch_bounds__(256) void amsr2_final(
        const float* __restrict__ pr, float* __restrict__ out)
{
    __shared__ double res[28];
    int wid = threadIdx.x >> 6, lane = threadIdx.x & 63;
    for (int c = wid; c < 28; c += 4) {
        const float* base; int n;
        if (c < 4)       { base = pr + c * NBLK; n = NBLK; }
        else if (c < 24) { int cc = c - 4; int s_ = 4 + (cc >> 2); int b_ = cc & 3;
                           base = pr + s_ * NBLK + b_ * 2048; n = 2048; }
        else             { int b_ = c - 24; base = pr + 9 * NBLK + b_ * 2048; n = 2048; }
        double sacc = 0.0;
        for (int i = lane; i < n; i += 64) sacc += (double)base[i];
        for (int off = 32; off > 0; off >>= 1) sacc += __shfl_down(sacc, off);
        if (lane == 0) res[c] = sacc;
    }
    __syncthreads();
    if (threadIdx.x == 0) {
        const double n = (double)NPIX;
        double l1   = res[0] / (4.0 * n);
        double grad = res[1] / (4.0 * 2047.0 * 2048.0) + res[2] / (4.0 * 2048.0 * 2047.0);
        double energy = 0.0, dist = 0.0, psnr_sum = 0.0, ssim_sum = 0.0;
        for (int b = 0; b < 4; ++b) {
            double Sp  = res[4 + b],  St  = res[8 + b];
            double Spp = res[12 + b], Stt = res[16 + b];
            double Su8 = res[20 + b], Sss = res[24 + b];
            double pm = Sp / n, tm = St / n;
            double dm = pm - tm; energy += dm * dm;
            double vp = (Spp - n * pm * pm) / (n - 1.0);
            double vt = (Stt - n * tm * tm) / (n - 1.0);
            double ps = sqrt(fmax(vp, 0.0)), ts = sqrt(fmax(vt, 0.0));
            double dd = ps - ts; dist += dd * dd;
            double mse = Su8 / n;
            double psnr = (mse == 0.0) ? 100.0 : 10.0 * log10(65025.0 / fmax(mse, 1e-12));
            psnr_sum += psnr;
            ssim_sum += Sss / ((double)OUTW * (double)OUTW);
        }
        energy *= 0.25; dist *= 0.25;
        double range_pen = res[3] / (4.0 * n);
        double phys = energy + 0.5 * dist + 0.1 * range_pen;
        double ssim_mean = fmin(fmax(ssim_sum * 0.25, 0.0), 1.0);
        double total = l1 + 0.15 * grad + 0.05 * phys + 0.1 * (1.0 - ssim_mean);
        out[0] = (float)total;
        out[1] = (float)(psnr_sum * 0.25);
        out[2] = (float)ssim_mean;
    }
}

extern "C" void kernel_launch(void* const* d_in, const int* in_sizes, int n_in,
                              void* d_out, int out_size, void* d_ws, size_t ws_size,
                              hipStream_t stream)
{
    (void)in_sizes; (void)n_in; (void)out_size; (void)ws_size;
    const float* pred = (const float*)d_in[0];
    const float* targ = (const float*)d_in[1];
    float* out = (float*)d_out;
    float* pr  = (float*)d_ws;            // 10 * 8192 floats of partials

    GaussW gw;                            // host-side f64 Gaussian, cast to f32
    {
        double e[11], sm = 0.0;
        for (int i = 0; i < 11; ++i) {
            double d = (double)(i - 5);
            e[i] = exp(-(d * d) / 4.5);
            sm += e[i];
        }
        for (int i = 0; i < 11; ++i) gw.g[i] = (float)(e[i] / sm);
    }

    amsr2_fused<<<dim3(64, 32, 4), 256, 0, stream>>>(pred, targ, pr, gw);
    amsr2_final<<<1, 256, 0, stream>>>(pr, out);
}

// Round 4
// 324.747 us; speedup vs baseline: 2.5729x; 1.6024x over previous
//
#include <hip/hip_runtime.h>
#include <math.h>

#define HDIM 2048
#define WDIM 2048
#define NPIX (HDIM*WDIM)
#define OUTW 2038          /* valid conv output size: 2048-10 */

#define C1F 6.5025f        /* (0.01*255)^2 */
#define C2F 58.5225f       /* (0.03*255)^2 */

constexpr int TH  = 64, TW = 32;   // output tile
constexpr int IH  = TH + 10;       // 74 input rows
constexpr int IWD = 11;            // dwords per LDS input row (44 cols, 42 used)
constexpr int HSH = 40;            // h-array row stride in halves (80 B rows, 16B-aligned stores)
constexpr int NBLK = 8192;         // 64 x 32 x 4

struct GaussW { float g[11]; };

typedef _Float16 h2v __attribute__((ext_vector_type(2)));
typedef _Float16 h4v __attribute__((ext_vector_type(4)));
typedef _Float16 h8v __attribute__((ext_vector_type(8)));

// quant: ref ((clip(x)+1)*0.5)*255 == (clip(x)+1)*127.5 bit-exactly (*0.5 is exact);
// floor+clip handled by trunc-clamp u8 convert (values are >= 0).
__device__ __forceinline__ float quant_val(float x) {
    return (fminf(fmaxf(x, -1.0f), 1.0f) + 1.0f) * 127.5f;
}

__device__ __forceinline__ unsigned pack4_u8(const float* v) {
#if __has_builtin(__builtin_amdgcn_cvt_pk_u8_f32)
    unsigned r = 0;
    r = __builtin_amdgcn_cvt_pk_u8_f32(v[0], 0, r);
    r = __builtin_amdgcn_cvt_pk_u8_f32(v[1], 1, r);
    r = __builtin_amdgcn_cvt_pk_u8_f32(v[2], 2, r);
    r = __builtin_amdgcn_cvt_pk_u8_f32(v[3], 3, r);
    return r;
#else
    return ((unsigned)(int)v[0]) | (((unsigned)(int)v[1]) << 8) |
           (((unsigned)(int)v[2]) << 16) | (((unsigned)(int)v[3]) << 24);
#endif
}

// 11-tap horizontal conv of 8 consecutive outputs in packed-f16.
// A[0..8]: aligned pairs, S[0..7]: one-shifted pairs, GE[6]/GO[5]: even/odd tap weights.
__device__ __forceinline__ h8v conv11(const h2v* A, const h2v* S,
                                      const h2v* GE, const h2v* GO) {
    union { h2v h2[4]; h8v h8; } u;
#pragma unroll
    for (int o = 0; o < 4; ++o) {
        h2v acc = GE[0] * A[o];
#pragma unroll
        for (int m = 1; m < 6; ++m) acc += GE[m] * A[o + m];
#pragma unroll
        for (int m = 0; m < 5; ++m) acc += GO[m] * S[o + m];
        u.h2[o] = acc;
    }
    return u.h8;
}

// ---------------------------------------------------------------------------
// Fused kernel: per 64x32 tile
//   stage A: load f32, pointwise stats on owned core, quantize+pack u8x4 -> LDS
//   stage B: packed-f16 horizontal 11-tap conv of {p,t,p2,t2,pt} (+ u8 SSE stat)
//   stage C: packed-f16 vertical 11-tap + SSIM map
//   partials: pr[c*8192 + bid], c = 0:l1 1:gxH 2:gyW 3:relu 4:sp 5:st
//             6:spp 7:stt 8:su8 9:ssim
// NOTE: plain __launch_bounds__(256); min-waves hints caused spill disaster (round 2).
// ---------------------------------------------------------------------------
__global__ __launch_bounds__(256) void amsr2_fused(
        const float* __restrict__ pred, const float* __restrict__ targ,
        float* __restrict__ pr, GaussW gw)
{
    __shared__ unsigned sp[IH * IWD];
    __shared__ unsigned st[IH * IWD];
    __shared__ alignas(16) _Float16 hp [IH*HSH];
    __shared__ alignas(16) _Float16 ht [IH*HSH];
    __shared__ alignas(16) _Float16 hpp[IH*HSH];
    __shared__ alignas(16) _Float16 htt[IH*HSH];
    __shared__ alignas(16) _Float16 hpt[IH*HSH];
    __shared__ float sred[4][10];

    float G[11];
#pragma unroll
    for (int i = 0; i < 11; ++i) G[i] = gw.g[i];

    const int b  = blockIdx.z;
    const int r0 = blockIdx.y * TH;
    const int c0 = blockIdx.x * TW;
    const float* pb = pred + (size_t)b * NPIX;
    const float* tb = targ + (size_t)b * NPIX;

    float s[9];
#pragma unroll
    for (int c = 0; c < 9; ++c) s[c] = 0.0f;

    // ---- stage A: load + stats (core) + quantize/pack into LDS ----
    for (int item = threadIdx.x; item < IH * IWD; item += 256) {
        int r = item / IWD, d = item - r * IWD;
        int gr = r0 + r, gc = c0 + d * 4;
        bool rowok = (gr < HDIM);
        float pv[4], tv[4];
        bool vec = rowok && (gc + 3 < WDIM);
        if (vec) {
            const float* prow = pb + (size_t)gr * WDIM + gc;
            const float* trow = tb + (size_t)gr * WDIM + gc;
            float4 a4 = *(const float4*)prow;
            float4 b4 = *(const float4*)trow;
            pv[0]=a4.x; pv[1]=a4.y; pv[2]=a4.z; pv[3]=a4.w;
            tv[0]=b4.x; tv[1]=b4.y; tv[2]=b4.z; tv[3]=b4.w;
            if (r < TH && d < 8) {               // owned core pixels: stats
                bool down = (gr + 1 < HDIM);
                float pd[4] = {0,0,0,0}, td[4] = {0,0,0,0};
                if (down) {
                    float4 a4d = *(const float4*)(prow + WDIM);
                    float4 b4d = *(const float4*)(trow + WDIM);
                    pd[0]=a4d.x; pd[1]=a4d.y; pd[2]=a4d.z; pd[3]=a4d.w;
                    td[0]=b4d.x; td[1]=b4d.y; td[2]=b4d.z; td[3]=b4d.w;
                }
                bool hasR = (gc + 4 < WDIM);
                float p5 = hasR ? prow[4] : 0.0f;
                float t5 = hasR ? trow[4] : 0.0f;
#pragma unroll
                for (int k = 0; k < 4; ++k) {
                    float av = pv[k], bv = tv[k];
                    float dd = av - bv;
                    s[0] += fabsf(dd);
                    s[3] += fmaxf(fabsf(av) - 1.0f, 0.0f);
                    s[4] += av;  s[5] += bv;
                    s[6] += av * av;  s[7] += bv * bv;
                    if (down) {                     // gradient along H
                        float dn = pd[k] - td[k];
                        s[1] += fabsf(dd - dn);
                    }
                    float nr  = (k < 3) ? pv[k+1] : p5;
                    float nrt = (k < 3) ? tv[k+1] : t5;
                    if (k < 3 || hasR) {            // gradient along W
                        s[2] += fabsf(dd - (nr - nrt));
                    }
                }
            }
        } else {
            const float* prow = pb + (size_t)gr * WDIM;
            const float* trow = tb + (size_t)gr * WDIM;
#pragma unroll
            for (int k = 0; k < 4; ++k) {
                int gcc = gc + k;
                bool ok = rowok && (gcc < WDIM);
                pv[k] = ok ? prow[gcc] : 0.0f;
                tv[k] = ok ? trow[gcc] : 0.0f;
            }
        }
        float qp[4], qt[4];
#pragma unroll
        for (int k = 0; k < 4; ++k) {
            bool ok = rowok && (d * 4 + k < 42) && (gc + k < WDIM);
            qp[k] = ok ? quant_val(pv[k]) : 0.0f;
            qt[k] = ok ? quant_val(tv[k]) : 0.0f;
        }
        sp[item] = pack4_u8(qp);
        st[item] = pack4_u8(qt);
    }
    __syncthreads();

    // ---- stage B: packed-f16 horizontal conv -> f16 LDS; fold in u8 SSE ----
    {
        h2v GE[6], GO[5];
#pragma unroll
        for (int m = 0; m < 6; ++m) { _Float16 w = (_Float16)G[2*m];   GE[m].x = w; GE[m].y = w; }
#pragma unroll
        for (int m = 0; m < 5; ++m) { _Float16 w = (_Float16)G[2*m+1]; GO[m].x = w; GO[m].y = w; }

        for (int item = threadIdx.x; item < IH * 4; item += 256) {
            int r = item >> 2, c8 = item & 3;
            int bs = r * IWD + c8 * 2;
            float fp[20], ft[20];
#pragma unroll
            for (int k = 0; k < 5; ++k) {
                unsigned a = sp[bs + k], c = st[bs + k];
#pragma unroll
                for (int e = 0; e < 4; ++e) {
                    fp[4*k+e] = (float)((a >> (8*e)) & 0xffu);
                    ft[4*k+e] = (float)((c >> (8*e)) & 0xffu);
                }
            }
            if (r < TH) {            // owned 8 output cols: u8 SSE, once per pixel
#pragma unroll
                for (int e = 0; e < 8; ++e) { float d = fp[e] - ft[e]; s[8] += d * d; }
            }
            h2v Pp[10], Pt[10];
#pragma unroll
            for (int k = 0; k < 10; ++k) {
                Pp[k] = __builtin_bit_cast(h2v, __builtin_amdgcn_cvt_pkrtz(fp[2*k], fp[2*k+1]));
                Pt[k] = __builtin_bit_cast(h2v, __builtin_amdgcn_cvt_pkrtz(ft[2*k], ft[2*k+1]));
            }
            h2v Sp[8], St2[8];
#pragma unroll
            for (int k = 0; k < 8; ++k) {
                h2v x; x.x = Pp[k].y; x.y = Pp[k+1].x; Sp[k]  = x;
                h2v y; y.x = Pt[k].y; y.y = Pt[k+1].x; St2[k] = y;
            }
            int hb = r * HSH + c8 * 8;
            *(h8v*)&hp[hb] = conv11(Pp, Sp, GE, GO);
            *(h8v*)&ht[hb] = conv11(Pt, St2, GE, GO);
            {
                h2v A[9], S2[8];
#pragma unroll
                for (int k = 0; k < 9; ++k) A[k] = Pp[k] * Pp[k];
#pragma unroll
                for (int k = 0; k < 8; ++k) S2[k] = Sp[k] * Sp[k];
                *(h8v*)&hpp[hb] = conv11(A, S2, GE, GO);
            }
            {
                h2v A[9], S2[8];
#pragma unroll
                for (int k = 0; k < 9; ++k) A[k] = Pt[k] * Pt[k];
#pragma unroll
                for (int k = 0; k < 8; ++k) S2[k] = St2[k] * St2[k];
                *(h8v*)&htt[hb] = conv11(A, S2, GE, GO);
            }
            {
                h2v A[9], S2[8];
#pragma unroll
                for (int k = 0; k < 9; ++k) A[k] = Pp[k] * Pt[k];
#pragma unroll
                for (int k = 0; k < 8; ++k) S2[k] = Sp[k] * St2[k];
                *(h8v*)&hpt[hb] = conv11(A, S2, GE, GO);
            }
        }
    }
    __syncthreads();

    // ---- stage C: packed-f16 vertical conv + SSIM; 2 rows x 4 cols/thread ----
    float ssum = 0.0f;
    {
        h2v GH[11];
#pragma unroll
        for (int j = 0; j < 11; ++j) { _Float16 w = (_Float16)G[j]; GH[j].x = w; GH[j].y = w; }

        int rp = threadIdx.x >> 3;   // 0..31  -> rows 2rp, 2rp+1
        int cg = threadIdx.x & 7;    // 0..7   -> cols 4cg..4cg+3
        h2v acc[2][5][2];
#pragma unroll
        for (int rr = 0; rr < 2; ++rr)
#pragma unroll
            for (int a = 0; a < 5; ++a)
#pragma unroll
                for (int q = 0; q < 2; ++q) { acc[rr][a][q].x = (_Float16)0; acc[rr][a][q].y = (_Float16)0; }
#pragma unroll
        for (int j = 0; j < 12; ++j) {
            int off = (2*rp + j) * HSH + cg * 4;
            union { h4v h4; h2v h2[2]; } v[5];
            v[0].h4 = *(const h4v*)&hp [off];
            v[1].h4 = *(const h4v*)&ht [off];
            v[2].h4 = *(const h4v*)&hpp[off];
            v[3].h4 = *(const h4v*)&htt[off];
            v[4].h4 = *(const h4v*)&hpt[off];
            if (j < 11) {
#pragma unroll
                for (int a = 0; a < 5; ++a)
#pragma unroll
                    for (int q = 0; q < 2; ++q) acc[0][a][q] += GH[j] * v[a].h2[q];
            }
            if (j >= 1) {
#pragma unroll
                for (int a = 0; a < 5; ++a)
#pragma unroll
                    for (int q = 0; q < 2; ++q) acc[1][a][q] += GH[j-1] * v[a].h2[q];
            }
        }
        int th_ = min(TH, OUTW - r0);
        int tw_ = min(TW, OUTW - c0);
#pragma unroll
        for (int rr = 0; rr < 2; ++rr) {
            if (2*rp + rr < th_) {
#pragma unroll
                for (int q = 0; q < 2; ++q) {
#pragma unroll
                    for (int e = 0; e < 2; ++e) {
                        if (cg*4 + 2*q + e < tw_) {
                            float mu1 = (float)acc[rr][0][q][e];
                            float mu2 = (float)acc[rr][1][q][e];
                            float vpp = (float)acc[rr][2][q][e];
                            float vtt = (float)acc[rr][3][q][e];
                            float vpt = (float)acc[rr][4][q][e];
                            float mu1s = mu1*mu1, mu2s = mu2*mu2, mu12 = mu1*mu2;
                            float sg1 = vpp - mu1s, sg2 = vtt - mu2s, sg12 = vpt - mu12;
                            float num = (2.0f*mu12 + C1F) * (2.0f*sg12 + C2F);
                            float den = (mu1s + mu2s + C1F) * (sg1 + sg2 + C2F);
                            ssum += num * __builtin_amdgcn_rcpf(den);
                        }
                    }
                }
            }
        }
    }

    // ---- block reduction of 10 partials ----
    float st10[10];
#pragma unroll
    for (int c = 0; c < 9; ++c) st10[c] = s[c];
    st10[9] = ssum;
#pragma unroll
    for (int c = 0; c < 10; ++c) {
        float v = st10[c];
        for (int off = 32; off > 0; off >>= 1) v += __shfl_down(v, off);
        st10[c] = v;
    }
    int lane = threadIdx.x & 63, wid = threadIdx.x >> 6;
    if (lane == 0) {
#pragma unroll
        for (int c = 0; c < 10; ++c) sred[wid][c] = st10[c];
    }
    __syncthreads();
    if (threadIdx.x < 10) {
        int c = threadIdx.x;
        int bid = ((blockIdx.z * 32) + blockIdx.y) * 64 + blockIdx.x;
        pr[c * NBLK + bid] = sred[0][c] + sred[1][c] + sred[2][c] + sred[3][c];
    }
}

// ---------------------------------------------------------------------------
// Final combine: 28 segments reduced wave-parallel in f64.
// ---------------------------------------------------------------------------
__global__ __launch_bounds__(256) void amsr2_final(
        const float* __restrict__ pr, float* __restrict__ out)
{
    __shared__ double res[28];
    int wid = threadIdx.x >> 6, lane = threadIdx.x & 63;
    for (int c = wid; c < 28; c += 4) {
        const float* base; int n;
        if (c < 4)       { base = pr + c * NBLK; n = NBLK; }
        else if (c < 24) { int cc = c - 4; int s_ = 4 + (cc >> 2); int b_ = cc & 3;
                           base = pr + s_ * NBLK + b_ * 2048; n = 2048; }
        else             { int b_ = c - 24; base = pr + 9 * NBLK + b_ * 2048; n = 2048; }
        double sacc = 0.0;
        for (int i = lane; i < n; i += 64) sacc += (double)base[i];
        for (int off = 32; off > 0; off >>= 1) sacc += __shfl_down(sacc, off);
        if (lane == 0) res[c] = sacc;
    }
    __syncthreads();
    if (threadIdx.x == 0) {
        const double n = (double)NPIX;
        double l1   = res[0] / (4.0 * n);
        double grad = res[1] / (4.0 * 2047.0 * 2048.0) + res[2] / (4.0 * 2048.0 * 2047.0);
        double energy = 0.0, dist = 0.0, psnr_sum = 0.0, ssim_sum = 0.0;
        for (int b = 0; b < 4; ++b) {
            double Sp  = res[4 + b],  St  = res[8 + b];
            double Spp = res[12 + b], Stt = res[16 + b];
            double Su8 = res[20 + b], Sss = res[24 + b];
            double pm = Sp / n, tm = St / n;
            double dm = pm - tm; energy += dm * dm;
            double vp = (Spp - n * pm * pm) / (n - 1.0);
            double vt = (Stt - n * tm * tm) / (n - 1.0);
            double ps = sqrt(fmax(vp, 0.0)), ts = sqrt(fmax(vt, 0.0));
            double dd = ps - ts; dist += dd * dd;
            double mse = Su8 / n;
            double psnr = (mse == 0.0) ? 100.0 : 10.0 * log10(65025.0 / fmax(mse, 1e-12));
            psnr_sum += psnr;
            ssim_sum += Sss / ((double)OUTW * (double)OUTW);
        }
        energy *= 0.25; dist *= 0.25;
        double range_pen = res[3] / (4.0 * n);
        double phys = energy + 0.5 * dist + 0.1 * range_pen;
        double ssim_mean = fmin(fmax(ssim_sum * 0.25, 0.0), 1.0);
        double total = l1 + 0.15 * grad + 0.05 * phys + 0.1 * (1.0 - ssim_mean);
        out[0] = (float)total;
        out[1] = (float)(psnr_sum * 0.25);
        out[2] = (float)ssim_mean;
    }
}

extern "C" void kernel_launch(void* const* d_in, const int* in_sizes, int n_in,
                              void* d_out, int out_size, void* d_ws, size_t ws_size,
                              hipStream_t stream)
{
    (void)in_sizes; (void)n_in; (void)out_size; (void)ws_size;
    const float* pred = (const float*)d_in[0];
    const float* targ = (const float*)d_in[1];
    float* out = (float*)d_out;
    float* pr  = (float*)d_ws;            // 10 * 8192 floats of partials

    GaussW gw;                            // host-side f64 Gaussian, cast to f32
    {
        double e[11], sm = 0.0;
        for (int i = 0; i < 11; ++i) {
            double d = (double)(i - 5);
            e[i] = exp(-(d * d) / 4.5);
            sm += e[i];
        }
        for (int i = 0; i < 11; ++i) gw.g[i] = (float)(e[i] / sm);
    }

    amsr2_fused<<<dim3(64, 32, 4), 256, 0, stream>>>(pred, targ, pr, gw);
    amsr2_final<<<1, 256, 0, stream>>>(pr, out);
}

// Round 5
// 299.695 us; speedup vs baseline: 2.7880x; 1.0836x over previous
//
#include <hip/hip_runtime.h>
#include <math.h>

#define HDIM 2048
#define WDIM 2048
#define NPIX (HDIM*WDIM)
#define OUTW 2038          /* valid conv output size: 2048-10 */

#define C1F 6.5025f        /* (0.01*255)^2 */
#define C2F 58.5225f       /* (0.03*255)^2 */

constexpr int TH  = 64, TW = 32;   // output tile
constexpr int IH  = TH + 10;       // 74 input rows
constexpr int IWD = 11;            // dwords per LDS input row (44 cols, 42 used)
constexpr int HSH = 40;            // h-array row stride in halves (80 B rows; bank-safe mod 32)

struct GaussW { float g[11]; };

typedef _Float16 h2v __attribute__((ext_vector_type(2)));
typedef _Float16 h4v __attribute__((ext_vector_type(4)));
typedef _Float16 h8v __attribute__((ext_vector_type(8)));

// quant: ref ((clip(x)+1)*0.5)*255 == (clip(x)+1)*127.5 bit-exactly (*0.5 is exact);
// floor+clip handled by trunc-clamp u8 convert (values are >= 0).
__device__ __forceinline__ float quant_val(float x) {
    return (fminf(fmaxf(x, -1.0f), 1.0f) + 1.0f) * 127.5f;
}

__device__ __forceinline__ unsigned pack4_u8(const float* v) {
#if __has_builtin(__builtin_amdgcn_cvt_pk_u8_f32)
    unsigned r = 0;
    r = __builtin_amdgcn_cvt_pk_u8_f32(v[0], 0, r);
    r = __builtin_amdgcn_cvt_pk_u8_f32(v[1], 1, r);
    r = __builtin_amdgcn_cvt_pk_u8_f32(v[2], 2, r);
    r = __builtin_amdgcn_cvt_pk_u8_f32(v[3], 3, r);
    return r;
#else
    return ((unsigned)(int)v[0]) | (((unsigned)(int)v[1]) << 8) |
           (((unsigned)(int)v[2]) << 16) | (((unsigned)(int)v[3]) << 24);
#endif
}

// 11-tap horizontal conv of 8 consecutive outputs in packed-f16.
__device__ __forceinline__ h8v conv11(const h2v* A, const h2v* S,
                                      const h2v* GE, const h2v* GO) {
    union { h2v h2[4]; h8v h8; } u;
#pragma unroll
    for (int o = 0; o < 4; ++o) {
        h2v acc = GE[0] * A[o];
#pragma unroll
        for (int m = 1; m < 6; ++m) acc += GE[m] * A[o + m];
#pragma unroll
        for (int m = 0; m < 5; ++m) acc += GO[m] * S[o + m];
        u.h2[o] = acc;
    }
    return u.h8;
}

// ---------------------------------------------------------------------------
// Fused kernel: per 64x32 tile; ends with 10 device-scope atomicAdds into a
// 40-slot (channel x image) accumulator (round 5: replaces the 320 KB
// per-block partial array whose single-block reduction cost ~170 us).
// Channels: 0:l1 1:gxH 2:gyW 3:relu 4:sp 5:st 6:spp 7:stt 8:su8 9:ssim
// ---------------------------------------------------------------------------
__global__ __launch_bounds__(256) void amsr2_fused(
        const float* __restrict__ pred, const float* __restrict__ targ,
        float* __restrict__ acc40, GaussW gw)
{
    __shared__ unsigned sp[IH * IWD];
    __shared__ unsigned st[IH * IWD];
    __shared__ alignas(16) _Float16 hp [IH*HSH];
    __shared__ alignas(16) _Float16 ht [IH*HSH];
    __shared__ alignas(16) _Float16 hpp[IH*HSH];
    __shared__ alignas(16) _Float16 htt[IH*HSH];
    __shared__ alignas(16) _Float16 hpt[IH*HSH];
    __shared__ float sred[4][10];

    float G[11];
#pragma unroll
    for (int i = 0; i < 11; ++i) G[i] = gw.g[i];

    const int b  = blockIdx.z;
    const int r0 = blockIdx.y * TH;
    const int c0 = blockIdx.x * TW;
    const float* pb = pred + (size_t)b * NPIX;
    const float* tb = targ + (size_t)b * NPIX;

    float s[9];
#pragma unroll
    for (int c = 0; c < 9; ++c) s[c] = 0.0f;

    // ---- stage A: load + stats (core) + quantize/pack into LDS ----
    for (int item = threadIdx.x; item < IH * IWD; item += 256) {
        int r = item / IWD, d = item - r * IWD;
        int gr = r0 + r, gc = c0 + d * 4;
        bool rowok = (gr < HDIM);
        float pv[4], tv[4];
        bool vec = rowok && (gc + 3 < WDIM);
        if (vec) {
            const float* prow = pb + (size_t)gr * WDIM + gc;
            const float* trow = tb + (size_t)gr * WDIM + gc;
            float4 a4 = *(const float4*)prow;
            float4 b4 = *(const float4*)trow;
            pv[0]=a4.x; pv[1]=a4.y; pv[2]=a4.z; pv[3]=a4.w;
            tv[0]=b4.x; tv[1]=b4.y; tv[2]=b4.z; tv[3]=b4.w;
            if (r < TH && d < 8) {               // owned core pixels: stats
                bool down = (gr + 1 < HDIM);
                float pd[4] = {0,0,0,0}, td[4] = {0,0,0,0};
                if (down) {
                    float4 a4d = *(const float4*)(prow + WDIM);
                    float4 b4d = *(const float4*)(trow + WDIM);
                    pd[0]=a4d.x; pd[1]=a4d.y; pd[2]=a4d.z; pd[3]=a4d.w;
                    td[0]=b4d.x; td[1]=b4d.y; td[2]=b4d.z; td[3]=b4d.w;
                }
                bool hasR = (gc + 4 < WDIM);
                float p5 = hasR ? prow[4] : 0.0f;
                float t5 = hasR ? trow[4] : 0.0f;
#pragma unroll
                for (int k = 0; k < 4; ++k) {
                    float av = pv[k], bv = tv[k];
                    float dd = av - bv;
                    s[0] += fabsf(dd);
                    s[3] += fmaxf(fabsf(av) - 1.0f, 0.0f);
                    s[4] += av;  s[5] += bv;
                    s[6] += av * av;  s[7] += bv * bv;
                    if (down) {                     // gradient along H
                        float dn = pd[k] - td[k];
                        s[1] += fabsf(dd - dn);
                    }
                    float nr  = (k < 3) ? pv[k+1] : p5;
                    float nrt = (k < 3) ? tv[k+1] : t5;
                    if (k < 3 || hasR) {            // gradient along W
                        s[2] += fabsf(dd - (nr - nrt));
                    }
                }
            }
        } else {
            const float* prow = pb + (size_t)gr * WDIM;
            const float* trow = tb + (size_t)gr * WDIM;
#pragma unroll
            for (int k = 0; k < 4; ++k) {
                int gcc = gc + k;
                bool ok = rowok && (gcc < WDIM);
                pv[k] = ok ? prow[gcc] : 0.0f;
                tv[k] = ok ? trow[gcc] : 0.0f;
            }
        }
        float qp[4], qt[4];
#pragma unroll
        for (int k = 0; k < 4; ++k) {
            bool ok = rowok && (d * 4 + k < 42) && (gc + k < WDIM);
            qp[k] = ok ? quant_val(pv[k]) : 0.0f;
            qt[k] = ok ? quant_val(tv[k]) : 0.0f;
        }
        sp[item] = pack4_u8(qp);
        st[item] = pack4_u8(qt);
    }
    __syncthreads();

    // ---- stage B: packed-f16 horizontal conv -> f16 LDS; fold in u8 SSE ----
    {
        h2v GE[6], GO[5];
#pragma unroll
        for (int m = 0; m < 6; ++m) { _Float16 w = (_Float16)G[2*m];   GE[m].x = w; GE[m].y = w; }
#pragma unroll
        for (int m = 0; m < 5; ++m) { _Float16 w = (_Float16)G[2*m+1]; GO[m].x = w; GO[m].y = w; }

        for (int item = threadIdx.x; item < IH * 4; item += 256) {
            int r = item >> 2, c8 = item & 3;
            int bs = r * IWD + c8 * 2;
            float fp[20], ft[20];
#pragma unroll
            for (int k = 0; k < 5; ++k) {
                unsigned a = sp[bs + k], c = st[bs + k];
#pragma unroll
                for (int e = 0; e < 4; ++e) {
                    fp[4*k+e] = (float)((a >> (8*e)) & 0xffu);
                    ft[4*k+e] = (float)((c >> (8*e)) & 0xffu);
                }
            }
            if (r < TH) {            // owned 8 output cols: u8 SSE, once per pixel
#pragma unroll
                for (int e = 0; e < 8; ++e) { float d = fp[e] - ft[e]; s[8] += d * d; }
            }
            h2v Pp[10], Pt[10];
#pragma unroll
            for (int k = 0; k < 10; ++k) {
                Pp[k] = __builtin_bit_cast(h2v, __builtin_amdgcn_cvt_pkrtz(fp[2*k], fp[2*k+1]));
                Pt[k] = __builtin_bit_cast(h2v, __builtin_amdgcn_cvt_pkrtz(ft[2*k], ft[2*k+1]));
            }
            h2v Sp[8], St2[8];
#pragma unroll
            for (int k = 0; k < 8; ++k) {
                h2v x; x.x = Pp[k].y; x.y = Pp[k+1].x; Sp[k]  = x;
                h2v y; y.x = Pt[k].y; y.y = Pt[k+1].x; St2[k] = y;
            }
            int hb = r * HSH + c8 * 8;
            *(h8v*)&hp[hb] = conv11(Pp, Sp, GE, GO);
            *(h8v*)&ht[hb] = conv11(Pt, St2, GE, GO);
            {
                h2v A[9], S2[8];
#pragma unroll
                for (int k = 0; k < 9; ++k) A[k] = Pp[k] * Pp[k];
#pragma unroll
                for (int k = 0; k < 8; ++k) S2[k] = Sp[k] * Sp[k];
                *(h8v*)&hpp[hb] = conv11(A, S2, GE, GO);
            }
            {
                h2v A[9], S2[8];
#pragma unroll
                for (int k = 0; k < 9; ++k) A[k] = Pt[k] * Pt[k];
#pragma unroll
                for (int k = 0; k < 8; ++k) S2[k] = St2[k] * St2[k];
                *(h8v*)&htt[hb] = conv11(A, S2, GE, GO);
            }
            {
                h2v A[9], S2[8];
#pragma unroll
                for (int k = 0; k < 9; ++k) A[k] = Pp[k] * Pt[k];
#pragma unroll
                for (int k = 0; k < 8; ++k) S2[k] = Sp[k] * St2[k];
                *(h8v*)&hpt[hb] = conv11(A, S2, GE, GO);
            }
        }
    }
    __syncthreads();

    // ---- stage C: packed-f16 vertical conv + SSIM; 2 rows x 4 cols/thread ----
    float ssum = 0.0f;
    {
        h2v GH[11];
#pragma unroll
        for (int j = 0; j < 11; ++j) { _Float16 w = (_Float16)G[j]; GH[j].x = w; GH[j].y = w; }

        int rp = threadIdx.x >> 3;   // 0..31  -> rows 2rp, 2rp+1
        int cg = threadIdx.x & 7;    // 0..7   -> cols 4cg..4cg+3
        h2v acc[2][5][2];
#pragma unroll
        for (int rr = 0; rr < 2; ++rr)
#pragma unroll
            for (int a = 0; a < 5; ++a)
#pragma unroll
                for (int q = 0; q < 2; ++q) { acc[rr][a][q].x = (_Float16)0; acc[rr][a][q].y = (_Float16)0; }
#pragma unroll
        for (int j = 0; j < 12; ++j) {
            int off = (2*rp + j) * HSH + cg * 4;
            union { h4v h4; h2v h2[2]; } v[5];
            v[0].h4 = *(const h4v*)&hp [off];
            v[1].h4 = *(const h4v*)&ht [off];
            v[2].h4 = *(const h4v*)&hpp[off];
            v[3].h4 = *(const h4v*)&htt[off];
            v[4].h4 = *(const h4v*)&hpt[off];
            if (j < 11) {
#pragma unroll
                for (int a = 0; a < 5; ++a)
#pragma unroll
                    for (int q = 0; q < 2; ++q) acc[0][a][q] += GH[j] * v[a].h2[q];
            }
            if (j >= 1) {
#pragma unroll
                for (int a = 0; a < 5; ++a)
#pragma unroll
                    for (int q = 0; q < 2; ++q) acc[1][a][q] += GH[j-1] * v[a].h2[q];
            }
        }
        int th_ = min(TH, OUTW - r0);
        int tw_ = min(TW, OUTW - c0);
#pragma unroll
        for (int rr = 0; rr < 2; ++rr) {
            if (2*rp + rr < th_) {
#pragma unroll
                for (int q = 0; q < 2; ++q) {
#pragma unroll
                    for (int e = 0; e < 2; ++e) {
                        if (cg*4 + 2*q + e < tw_) {
                            float mu1 = (float)acc[rr][0][q][e];
                            float mu2 = (float)acc[rr][1][q][e];
                            float vpp = (float)acc[rr][2][q][e];
                            float vtt = (float)acc[rr][3][q][e];
                            float vpt = (float)acc[rr][4][q][e];
                            float mu1s = mu1*mu1, mu2s = mu2*mu2, mu12 = mu1*mu2;
                            float sg1 = vpp - mu1s, sg2 = vtt - mu2s, sg12 = vpt - mu12;
                            float num = (2.0f*mu12 + C1F) * (2.0f*sg12 + C2F);
                            float den = (mu1s + mu2s + C1F) * (sg1 + sg2 + C2F);
                            ssum += num * __builtin_amdgcn_rcpf(den);
                        }
                    }
                }
            }
        }
    }

    // ---- block reduction of 10 partials + atomic accumulate ----
    float st10[10];
#pragma unroll
    for (int c = 0; c < 9; ++c) st10[c] = s[c];
    st10[9] = ssum;
#pragma unroll
    for (int c = 0; c < 10; ++c) {
        float v = st10[c];
        for (int off = 32; off > 0; off >>= 1) v += __shfl_down(v, off);
        st10[c] = v;
    }
    int lane = threadIdx.x & 63, wid = threadIdx.x >> 6;
    if (lane == 0) {
#pragma unroll
        for (int c = 0; c < 10; ++c) sred[wid][c] = st10[c];
    }
    __syncthreads();
    if (threadIdx.x < 10) {
        int c = threadIdx.x;
        float v = sred[0][c] + sred[1][c] + sred[2][c] + sred[3][c];
        atomicAdd(&acc40[c * 4 + b], v);
    }
}

// ---------------------------------------------------------------------------
// Final combine: read 40 floats, compute (total, psnr_mean, ssim_mean) in f64.
// ---------------------------------------------------------------------------
__global__ __launch_bounds__(64) void amsr2_final(
        const float* __restrict__ acc40, float* __restrict__ out)
{
    if (threadIdx.x != 0) return;
    double r[40];
    for (int i = 0; i < 40; ++i) r[i] = (double)acc40[i];
    const double n = (double)NPIX;
    double sum0 = 0, sum1 = 0, sum2 = 0, sum3 = 0;
    for (int b = 0; b < 4; ++b) {
        sum0 += r[0*4+b]; sum1 += r[1*4+b]; sum2 += r[2*4+b]; sum3 += r[3*4+b];
    }
    double l1   = sum0 / (4.0 * n);
    double grad = sum1 / (4.0 * 2047.0 * 2048.0) + sum2 / (4.0 * 2048.0 * 2047.0);
    double energy = 0.0, dist = 0.0, psnr_sum = 0.0, ssim_sum = 0.0;
    for (int b = 0; b < 4; ++b) {
        double Sp  = r[4*4+b],  St  = r[5*4+b];
        double Spp = r[6*4+b],  Stt = r[7*4+b];
        double Su8 = r[8*4+b],  Sss = r[9*4+b];
        double pm = Sp / n, tm = St / n;
        double dm = pm - tm; energy += dm * dm;
        double vp = (Spp - n * pm * pm) / (n - 1.0);
        double vt = (Stt - n * tm * tm) / (n - 1.0);
        double ps = sqrt(fmax(vp, 0.0)), ts = sqrt(fmax(vt, 0.0));
        double dd = ps - ts; dist += dd * dd;
        double mse = Su8 / n;
        double psnr = (mse == 0.0) ? 100.0 : 10.0 * log10(65025.0 / fmax(mse, 1e-12));
        psnr_sum += psnr;
        ssim_sum += Sss / ((double)OUTW * (double)OUTW);
    }
    energy *= 0.25; dist *= 0.25;
    double range_pen = sum3 / (4.0 * n);
    double phys = energy + 0.5 * dist + 0.1 * range_pen;
    double ssim_mean = fmin(fmax(ssim_sum * 0.25, 0.0), 1.0);
    double total = l1 + 0.15 * grad + 0.05 * phys + 0.1 * (1.0 - ssim_mean);
    out[0] = (float)total;
    out[1] = (float)(psnr_sum * 0.25);
    out[2] = (float)ssim_mean;
}

extern "C" void kernel_launch(void* const* d_in, const int* in_sizes, int n_in,
                              void* d_out, int out_size, void* d_ws, size_t ws_size,
                              hipStream_t stream)
{
    (void)in_sizes; (void)n_in; (void)out_size; (void)ws_size;
    const float* pred = (const float*)d_in[0];
    const float* targ = (const float*)d_in[1];
    float* out   = (float*)d_out;
    float* acc40 = (float*)d_ws;          // 40-slot atomic accumulator

    GaussW gw;                            // host-side f64 Gaussian, cast to f32
    {
        double e[11], sm = 0.0;
        for (int i = 0; i < 11; ++i) {
            double d = (double)(i - 5);
            e[i] = exp(-(d * d) / 4.5);
            sm += e[i];
        }
        for (int i = 0; i < 11; ++i) gw.g[i] = (float)(e[i] / sm);
    }

    hipMemsetAsync(acc40, 0, 40 * sizeof(float), stream);
    amsr2_fused<<<dim3(64, 32, 4), 256, 0, stream>>>(pred, targ, acc40, gw);
    amsr2_final<<<1, 64, 0, stream>>>(acc40, out);
}

// Round 6
// 242.535 us; speedup vs baseline: 3.4451x; 1.2357x over previous
//
#include <hip/hip_runtime.h>
#include <math.h>

#define HDIM 2048
#define WDIM 2048
#define NPIX (HDIM*WDIM)
#define OUTW 2038          /* valid conv output size: 2048-10 */

#define C1F 6.5025f        /* (0.01*255)^2 */
#define C2F 58.5225f       /* (0.03*255)^2 */

constexpr int TH  = 64, TW = 32;   // output tile
constexpr int IH  = TH + 10;       // 74 input rows
constexpr int IWD = 11;            // dwords per LDS input row (44 cols, 42 used)
constexpr int HSH = 40;            // h-array row stride in halves (80 B rows)
constexpr int NBLK = 8192;         // 64 x 32 x 4 blocks

struct GaussW { float g[11]; };

typedef _Float16 h2v __attribute__((ext_vector_type(2)));
typedef _Float16 h4v __attribute__((ext_vector_type(4)));
typedef _Float16 h8v __attribute__((ext_vector_type(8)));

// quant: ref ((clip(x)+1)*0.5)*255 == (clip(x)+1)*127.5 bit-exactly (*0.5 is exact);
// floor+clip handled by trunc-clamp u8 convert (values are >= 0).
__device__ __forceinline__ float quant_val(float x) {
    return (fminf(fmaxf(x, -1.0f), 1.0f) + 1.0f) * 127.5f;
}

__device__ __forceinline__ unsigned pack4_u8(const float* v) {
#if __has_builtin(__builtin_amdgcn_cvt_pk_u8_f32)
    unsigned r = 0;
    r = __builtin_amdgcn_cvt_pk_u8_f32(v[0], 0, r);
    r = __builtin_amdgcn_cvt_pk_u8_f32(v[1], 1, r);
    r = __builtin_amdgcn_cvt_pk_u8_f32(v[2], 2, r);
    r = __builtin_amdgcn_cvt_pk_u8_f32(v[3], 3, r);
    return r;
#else
    return ((unsigned)(int)v[0]) | (((unsigned)(int)v[1]) << 8) |
           (((unsigned)(int)v[2]) << 16) | (((unsigned)(int)v[3]) << 24);
#endif
}

// 11-tap horizontal conv of 8 consecutive outputs in packed-f16.
__device__ __forceinline__ h8v conv11(const h2v* A, const h2v* S,
                                      const h2v* GE, const h2v* GO) {
    union { h2v h2[4]; h8v h8; } u;
#pragma unroll
    for (int o = 0; o < 4; ++o) {
        h2v acc = GE[0] * A[o];
#pragma unroll
        for (int m = 1; m < 6; ++m) acc += GE[m] * A[o + m];
#pragma unroll
        for (int m = 0; m < 5; ++m) acc += GO[m] * S[o + m];
        u.h2[o] = acc;
    }
    return u.h8;
}

// ---------------------------------------------------------------------------
// Fused kernel: per 64x32 tile. Tail = 10 plain stores per block (round 6:
// the 40-hot-address atomic tail of round 5 serialized ~82k atomics at the
// coherent point and cost +45 us inside this kernel).
// Channels: 0:l1 1:gxH 2:gyW 3:relu 4:sp 5:st 6:spp 7:stt 8:su8 9:ssim
// Layout: pr[c*8192 + b*2048 + by*64 + bx]  (image-contiguous per channel)
// ---------------------------------------------------------------------------
__global__ __launch_bounds__(256) void amsr2_fused(
        const float* __restrict__ pred, const float* __restrict__ targ,
        float* __restrict__ pr, GaussW gw)
{
    __shared__ unsigned sp[IH * IWD];
    __shared__ unsigned st[IH * IWD];
    __shared__ alignas(16) _Float16 hp [IH*HSH];
    __shared__ alignas(16) _Float16 ht [IH*HSH];
    __shared__ alignas(16) _Float16 hpp[IH*HSH];
    __shared__ alignas(16) _Float16 htt[IH*HSH];
    __shared__ alignas(16) _Float16 hpt[IH*HSH];
    __shared__ float sred[4][10];

    float G[11];
#pragma unroll
    for (int i = 0; i < 11; ++i) G[i] = gw.g[i];

    const int b  = blockIdx.z;
    const int r0 = blockIdx.y * TH;
    const int c0 = blockIdx.x * TW;
    const float* pb = pred + (size_t)b * NPIX;
    const float* tb = targ + (size_t)b * NPIX;

    float s[9];
#pragma unroll
    for (int c = 0; c < 9; ++c) s[c] = 0.0f;

    // ---- stage A: load + stats (core) + quantize/pack into LDS ----
    for (int item = threadIdx.x; item < IH * IWD; item += 256) {
        int r = item / IWD, d = item - r * IWD;
        int gr = r0 + r, gc = c0 + d * 4;
        bool rowok = (gr < HDIM);
        float pv[4], tv[4];
        bool vec = rowok && (gc + 3 < WDIM);
        if (vec) {
            const float* prow = pb + (size_t)gr * WDIM + gc;
            const float* trow = tb + (size_t)gr * WDIM + gc;
            float4 a4 = *(const float4*)prow;
            float4 b4 = *(const float4*)trow;
            pv[0]=a4.x; pv[1]=a4.y; pv[2]=a4.z; pv[3]=a4.w;
            tv[0]=b4.x; tv[1]=b4.y; tv[2]=b4.z; tv[3]=b4.w;
            if (r < TH && d < 8) {               // owned core pixels: stats
                bool down = (gr + 1 < HDIM);
                float pd[4] = {0,0,0,0}, td[4] = {0,0,0,0};
                if (down) {
                    float4 a4d = *(const float4*)(prow + WDIM);
                    float4 b4d = *(const float4*)(trow + WDIM);
                    pd[0]=a4d.x; pd[1]=a4d.y; pd[2]=a4d.z; pd[3]=a4d.w;
                    td[0]=b4d.x; td[1]=b4d.y; td[2]=b4d.z; td[3]=b4d.w;
                }
                bool hasR = (gc + 4 < WDIM);
                float p5 = hasR ? prow[4] : 0.0f;
                float t5 = hasR ? trow[4] : 0.0f;
#pragma unroll
                for (int k = 0; k < 4; ++k) {
                    float av = pv[k], bv = tv[k];
                    float dd = av - bv;
                    s[0] += fabsf(dd);
                    s[3] += fmaxf(fabsf(av) - 1.0f, 0.0f);
                    s[4] += av;  s[5] += bv;
                    s[6] += av * av;  s[7] += bv * bv;
                    if (down) {                     // gradient along H
                        float dn = pd[k] - td[k];
                        s[1] += fabsf(dd - dn);
                    }
                    float nr  = (k < 3) ? pv[k+1] : p5;
                    float nrt = (k < 3) ? tv[k+1] : t5;
                    if (k < 3 || hasR) {            // gradient along W
                        s[2] += fabsf(dd - (nr - nrt));
                    }
                }
            }
        } else {
            const float* prow = pb + (size_t)gr * WDIM;
            const float* trow = tb + (size_t)gr * WDIM;
#pragma unroll
            for (int k = 0; k < 4; ++k) {
                int gcc = gc + k;
                bool ok = rowok && (gcc < WDIM);
                pv[k] = ok ? prow[gcc] : 0.0f;
                tv[k] = ok ? trow[gcc] : 0.0f;
            }
        }
        float qp[4], qt[4];
#pragma unroll
        for (int k = 0; k < 4; ++k) {
            bool ok = rowok && (d * 4 + k < 42) && (gc + k < WDIM);
            qp[k] = ok ? quant_val(pv[k]) : 0.0f;
            qt[k] = ok ? quant_val(tv[k]) : 0.0f;
        }
        sp[item] = pack4_u8(qp);
        st[item] = pack4_u8(qt);
    }
    __syncthreads();

    // ---- stage B: packed-f16 horizontal conv -> f16 LDS; fold in u8 SSE ----
    {
        h2v GE[6], GO[5];
#pragma unroll
        for (int m = 0; m < 6; ++m) { _Float16 w = (_Float16)G[2*m];   GE[m].x = w; GE[m].y = w; }
#pragma unroll
        for (int m = 0; m < 5; ++m) { _Float16 w = (_Float16)G[2*m+1]; GO[m].x = w; GO[m].y = w; }

        for (int item = threadIdx.x; item < IH * 4; item += 256) {
            int r = item >> 2, c8 = item & 3;
            int bs = r * IWD + c8 * 2;
            float fp[20], ft[20];
#pragma unroll
            for (int k = 0; k < 5; ++k) {
                unsigned a = sp[bs + k], c = st[bs + k];
#pragma unroll
                for (int e = 0; e < 4; ++e) {
                    fp[4*k+e] = (float)((a >> (8*e)) & 0xffu);
                    ft[4*k+e] = (float)((c >> (8*e)) & 0xffu);
                }
            }
            if (r < TH) {            // owned 8 output cols: u8 SSE, once per pixel
#pragma unroll
                for (int e = 0; e < 8; ++e) { float d = fp[e] - ft[e]; s[8] += d * d; }
            }
            h2v Pp[10], Pt[10];
#pragma unroll
            for (int k = 0; k < 10; ++k) {
                Pp[k] = __builtin_bit_cast(h2v, __builtin_amdgcn_cvt_pkrtz(fp[2*k], fp[2*k+1]));
                Pt[k] = __builtin_bit_cast(h2v, __builtin_amdgcn_cvt_pkrtz(ft[2*k], ft[2*k+1]));
            }
            h2v Sp[8], St2[8];
#pragma unroll
            for (int k = 0; k < 8; ++k) {
                h2v x; x.x = Pp[k].y; x.y = Pp[k+1].x; Sp[k]  = x;
                h2v y; y.x = Pt[k].y; y.y = Pt[k+1].x; St2[k] = y;
            }
            int hb = r * HSH + c8 * 8;
            *(h8v*)&hp[hb] = conv11(Pp, Sp, GE, GO);
            *(h8v*)&ht[hb] = conv11(Pt, St2, GE, GO);
            {
                h2v A[9], S2[8];
#pragma unroll
                for (int k = 0; k < 9; ++k) A[k] = Pp[k] * Pp[k];
#pragma unroll
                for (int k = 0; k < 8; ++k) S2[k] = Sp[k] * Sp[k];
                *(h8v*)&hpp[hb] = conv11(A, S2, GE, GO);
            }
            {
                h2v A[9], S2[8];
#pragma unroll
                for (int k = 0; k < 9; ++k) A[k] = Pt[k] * Pt[k];
#pragma unroll
                for (int k = 0; k < 8; ++k) S2[k] = St2[k] * St2[k];
                *(h8v*)&htt[hb] = conv11(A, S2, GE, GO);
            }
            {
                h2v A[9], S2[8];
#pragma unroll
                for (int k = 0; k < 9; ++k) A[k] = Pp[k] * Pt[k];
#pragma unroll
                for (int k = 0; k < 8; ++k) S2[k] = Sp[k] * St2[k];
                *(h8v*)&hpt[hb] = conv11(A, S2, GE, GO);
            }
        }
    }
    __syncthreads();

    // ---- stage C: packed-f16 vertical conv + SSIM; 2 rows x 4 cols/thread ----
    float ssum = 0.0f;
    {
        h2v GH[11];
#pragma unroll
        for (int j = 0; j < 11; ++j) { _Float16 w = (_Float16)G[j]; GH[j].x = w; GH[j].y = w; }

        int rp = threadIdx.x >> 3;   // 0..31  -> rows 2rp, 2rp+1
        int cg = threadIdx.x & 7;    // 0..7   -> cols 4cg..4cg+3
        h2v acc[2][5][2];
#pragma unroll
        for (int rr = 0; rr < 2; ++rr)
#pragma unroll
            for (int a = 0; a < 5; ++a)
#pragma unroll
                for (int q = 0; q < 2; ++q) { acc[rr][a][q].x = (_Float16)0; acc[rr][a][q].y = (_Float16)0; }
#pragma unroll
        for (int j = 0; j < 12; ++j) {
            int off = (2*rp + j) * HSH + cg * 4;
            union { h4v h4; h2v h2[2]; } v[5];
            v[0].h4 = *(const h4v*)&hp [off];
            v[1].h4 = *(const h4v*)&ht [off];
            v[2].h4 = *(const h4v*)&hpp[off];
            v[3].h4 = *(const h4v*)&htt[off];
            v[4].h4 = *(const h4v*)&hpt[off];
            if (j < 11) {
#pragma unroll
                for (int a = 0; a < 5; ++a)
#pragma unroll
                    for (int q = 0; q < 2; ++q) acc[0][a][q] += GH[j] * v[a].h2[q];
            }
            if (j >= 1) {
#pragma unroll
                for (int a = 0; a < 5; ++a)
#pragma unroll
                    for (int q = 0; q < 2; ++q) acc[1][a][q] += GH[j-1] * v[a].h2[q];
            }
        }
        int th_ = min(TH, OUTW - r0);
        int tw_ = min(TW, OUTW - c0);
#pragma unroll
        for (int rr = 0; rr < 2; ++rr) {
            if (2*rp + rr < th_) {
#pragma unroll
                for (int q = 0; q < 2; ++q) {
#pragma unroll
                    for (int e = 0; e < 2; ++e) {
                        if (cg*4 + 2*q + e < tw_) {
                            float mu1 = (float)acc[rr][0][q][e];
                            float mu2 = (float)acc[rr][1][q][e];
                            float vpp = (float)acc[rr][2][q][e];
                            float vtt = (float)acc[rr][3][q][e];
                            float vpt = (float)acc[rr][4][q][e];
                            float mu1s = mu1*mu1, mu2s = mu2*mu2, mu12 = mu1*mu2;
                            float sg1 = vpp - mu1s, sg2 = vtt - mu2s, sg12 = vpt - mu12;
                            float num = (2.0f*mu12 + C1F) * (2.0f*sg12 + C2F);
                            float den = (mu1s + mu2s + C1F) * (sg1 + sg2 + C2F);
                            ssum += num * __builtin_amdgcn_rcpf(den);
                        }
                    }
                }
            }
        }
    }

    // ---- block reduction of 10 partials; plain per-block stores ----
    float st10[10];
#pragma unroll
    for (int c = 0; c < 9; ++c) st10[c] = s[c];
    st10[9] = ssum;
#pragma unroll
    for (int c = 0; c < 10; ++c) {
        float v = st10[c];
        for (int off = 32; off > 0; off >>= 1) v += __shfl_down(v, off);
        st10[c] = v;
    }
    int lane = threadIdx.x & 63, wid = threadIdx.x >> 6;
    if (lane == 0) {
#pragma unroll
        for (int c = 0; c < 10; ++c) sred[wid][c] = st10[c];
    }
    __syncthreads();
    if (threadIdx.x < 10) {
        int c = threadIdx.x;
        int bid = ((b * 32) + blockIdx.y) * 64 + blockIdx.x;   // = b*2048 + by*64 + bx
        pr[c * NBLK + bid] = sred[0][c] + sred[1][c] + sred[2][c] + sred[3][c];
    }
}

// ---------------------------------------------------------------------------
// Final: ONE block, 256 threads. 40 segments (channel x image), each 2048
// CONTIGUOUS floats -> wave reads them as 8 independent float4/lane
// (coalesced, latency-hidden), f64 shfl-reduce. Thread 0 does scalar math.
// ---------------------------------------------------------------------------
__global__ __launch_bounds__(256) void amsr2_final(
        const float* __restrict__ pr, float* __restrict__ out)
{
    __shared__ double seg[40];
    int wid = threadIdx.x >> 6, lane = threadIdx.x & 63;
    for (int sidx = wid; sidx < 40; sidx += 4) {
        int c = sidx >> 2, b = sidx & 3;
        const float* base = pr + c * NBLK + b * 2048;
        float4 v[8];
#pragma unroll
        for (int it = 0; it < 8; ++it)
            v[it] = *(const float4*)(base + (it * 64 + lane) * 4);
        double acc = 0.0;
#pragma unroll
        for (int it = 0; it < 8; ++it)
            acc += (double)v[it].x + (double)v[it].y + (double)v[it].z + (double)v[it].w;
        for (int off = 32; off > 0; off >>= 1) acc += __shfl_down(acc, off);
        if (lane == 0) seg[sidx] = acc;
    }
    __syncthreads();
    if (threadIdx.x != 0) return;
    const double n = (double)NPIX;
    double sum0 = 0, sum1 = 0, sum2 = 0, sum3 = 0;
    for (int b = 0; b < 4; ++b) {
        sum0 += seg[0*4+b]; sum1 += seg[1*4+b]; sum2 += seg[2*4+b]; sum3 += seg[3*4+b];
    }
    double l1   = sum0 / (4.0 * n);
    double grad = sum1 / (4.0 * 2047.0 * 2048.0) + sum2 / (4.0 * 2048.0 * 2047.0);
    double energy = 0.0, dist = 0.0, psnr_sum = 0.0, ssim_sum = 0.0;
    for (int b = 0; b < 4; ++b) {
        double Sp  = seg[4*4+b],  St  = seg[5*4+b];
        double Spp = seg[6*4+b],  Stt = seg[7*4+b];
        double Su8 = seg[8*4+b],  Sss = seg[9*4+b];
        double pm = Sp / n, tm = St / n;
        double dm = pm - tm; energy += dm * dm;
        double vp = (Spp - n * pm * pm) / (n - 1.0);
        double vt = (Stt - n * tm * tm) / (n - 1.0);
        double ps = sqrt(fmax(vp, 0.0)), ts = sqrt(fmax(vt, 0.0));
        double dd = ps - ts; dist += dd * dd;
        double mse = Su8 / n;
        double psnr = (mse == 0.0) ? 100.0 : 10.0 * log10(65025.0 / fmax(mse, 1e-12));
        psnr_sum += psnr;
        ssim_sum += Sss / ((double)OUTW * (double)OUTW);
    }
    energy *= 0.25; dist *= 0.25;
    double range_pen = sum3 / (4.0 * n);
    double phys = energy + 0.5 * dist + 0.1 * range_pen;
    double ssim_mean = fmin(fmax(ssim_sum * 0.25, 0.0), 1.0);
    double total = l1 + 0.15 * grad + 0.05 * phys + 0.1 * (1.0 - ssim_mean);
    out[0] = (float)total;
    out[1] = (float)(psnr_sum * 0.25);
    out[2] = (float)ssim_mean;
}

extern "C" void kernel_launch(void* const* d_in, const int* in_sizes, int n_in,
                              void* d_out, int out_size, void* d_ws, size_t ws_size,
                              hipStream_t stream)
{
    (void)in_sizes; (void)n_in; (void)out_size; (void)ws_size;
    const float* pred = (const float*)d_in[0];
    const float* targ = (const float*)d_in[1];
    float* out = (float*)d_out;
    float* pr  = (float*)d_ws;            // 10 * 8192 floats of per-block partials

    GaussW gw;                            // host-side f64 Gaussian, cast to f32
    {
        double e[11], sm = 0.0;
        for (int i = 0; i < 11; ++i) {
            double d = (double)(i - 5);
            e[i] = exp(-(d * d) / 4.5);
            sm += e[i];
        }
        for (int i = 0; i < 11; ++i) gw.g[i] = (float)(e[i] / sm);
    }

    amsr2_fused<<<dim3(64, 32, 4), 256, 0, stream>>>(pred, targ, pr, gw);
    amsr2_final<<<1, 256, 0, stream>>>(pr, out);
}

// Round 7
// 191.547 us; speedup vs baseline: 4.3622x; 1.2662x over previous
//
#include <hip/hip_runtime.h>
#include <math.h>

#define HDIM 2048
#define WDIM 2048
#define NPIX (HDIM*WDIM)
#define OUTW 2038          /* valid conv output size: 2048-10 */

#define C1F 6.5025f        /* (0.01*255)^2 */
#define C2F 58.5225f       /* (0.03*255)^2 */

constexpr int TH   = 64, TW = 32;  // output tile
constexpr int IN_R = 80;           // input rows staged (5 MFMA row-blocks of 16)
constexpr int IN_S = 56;           // In row stride in f16 (112 B; 28 dw -> 2-way banks)
constexpr int HT_S = 88;           // H_T stride along r in f16 (176 B; 2-way banks)
constexpr int NBLK = 8192;         // 64 x 32 x 4 blocks

struct GaussW { float g[11]; };

typedef _Float16 half8 __attribute__((ext_vector_type(8)));
typedef float    f32x4 __attribute__((ext_vector_type(4)));

// quant: bit-exact vs reference sequence. (clip(x)+1)*0.5 then *255 ==
// (clip(x)+1)*127.5 (the *0.5 is exact); trunc == floor for v >= 0.
__device__ __forceinline__ float quant_u8f(float x) {
    float c = __builtin_amdgcn_fmed3f(x, -1.0f, 1.0f);
    return truncf((c + 1.0f) * 127.5f);
}

__device__ __forceinline__ unsigned pk2(float a, float b) {
    return __builtin_bit_cast(unsigned, __builtin_amdgcn_cvt_pkrtz(a, b));
}

// ---------------------------------------------------------------------------
// Fused kernel, MFMA edition. Per 64x32 tile:
//   stage A: load f32, pointwise stats on owned core, quantize -> f16 LDS rows
//   stage H: horizontal 11-tap conv as mfma_f32_16x16x32_f16, A = data rows,
//            B = banded Gaussian T; pp/tt/pt formed on A-fragments (pk_mul).
//            D written TRANSPOSED (C-layout rows contiguous -> b64) to H_T.
//   stage V: vertical 11-tap conv as MFMA, A = same T fragment, B = H_T b128.
//            SSIM map elementwise on the 5 aligned C/D fragments.
// Channels: 0:l1 1:gxH 2:gyW 3:relu 4:sp 5:st 6:spp 7:stt 8:su8 9:ssim
// ---------------------------------------------------------------------------
__global__ __launch_bounds__(256) void amsr2_fused(
        const float* __restrict__ pred, const float* __restrict__ targ,
        float* __restrict__ pr, GaussW gw)
{
    __shared__ alignas(16) _Float16 Ip[IN_R * IN_S];
    __shared__ alignas(16) _Float16 It[IN_R * IN_S];
    __shared__ alignas(16) _Float16 HT[5][32 * HT_S];
    __shared__ alignas(16) _Float16 Tg[16 * 32];      // T[n][k] = g[k-n]
    __shared__ float sred[4][10];

    const int b  = blockIdx.z;
    const int r0 = blockIdx.y * TH;
    const int c0 = blockIdx.x * TW;
    const float* pb = pred + (size_t)b * NPIX;
    const float* tb = targ + (size_t)b * NPIX;
    const bool interior = (blockIdx.y < 31) && (blockIdx.x < 63);

    // ---- banded Gaussian table (threads 0..15; each owns its row) ----
    if (threadIdx.x < 16) {
        int n = threadIdx.x;
#pragma unroll
        for (int i = 0; i < 16; ++i) ((unsigned*)Tg)[n * 16 + i] = 0u;
#pragma unroll
        for (int j = 0; j < 11; ++j) Tg[n * 32 + n + j] = (_Float16)gw.g[j];
    }

    float s[9];
#pragma unroll
    for (int c = 0; c < 9; ++c) s[c] = 0.0f;

    // ---- stage A: 80 rows x 48 cols staged; core(512) + halo(256+192) ----
    if (interior) {
        // core items: 64 rows x 8 dword-groups (cols 0..31) -- fully unguarded
#pragma unroll
        for (int i = 0; i < 2; ++i) {
            int item = threadIdx.x + i * 256;
            int r = item >> 3, d = item & 7;
            const float* prow = pb + (size_t)(r0 + r) * WDIM + (c0 + d * 4);
            const float* trow = tb + (size_t)(r0 + r) * WDIM + (c0 + d * 4);
            float4 a4 = *(const float4*)prow;
            float4 b4 = *(const float4*)trow;
            float4 ad = *(const float4*)(prow + WDIM);
            float4 bd = *(const float4*)(trow + WDIM);
            float p5 = prow[4], t5 = trow[4];
            float pv[4] = {a4.x, a4.y, a4.z, a4.w};
            float tv[4] = {b4.x, b4.y, b4.z, b4.w};
            float pd[4] = {ad.x, ad.y, ad.z, ad.w};
            float td[4] = {bd.x, bd.y, bd.z, bd.w};
            float qp[4], qt[4];
#pragma unroll
            for (int k = 0; k < 4; ++k) { qp[k] = quant_u8f(pv[k]); qt[k] = quant_u8f(tv[k]); }
#pragma unroll
            for (int k = 0; k < 4; ++k) {
                float av = pv[k], bv = tv[k];
                float dd = av - bv;
                s[0] += fabsf(dd);
                s[3] += fmaxf(fabsf(av) - 1.0f, 0.0f);
                s[4] += av;  s[5] += bv;
                s[6] = fmaf(av, av, s[6]);
                s[7] = fmaf(bv, bv, s[7]);
                s[1] += fabsf(dd - (pd[k] - td[k]));
                float nr  = (k < 3) ? pv[k + 1] : p5;
                float nt2 = (k < 3) ? tv[k + 1] : t5;
                s[2] += fabsf(dd - (nr - nt2));
                float qd = qp[k] - qt[k];
                s[8] = fmaf(qd, qd, s[8]);
            }
            *(uint2*)&Ip[r * IN_S + d * 4] = make_uint2(pk2(qp[0], qp[1]), pk2(qp[2], qp[3]));
            *(uint2*)&It[r * IN_S + d * 4] = make_uint2(pk2(qt[0], qt[1]), pk2(qt[2], qt[3]));
        }
        // halo 0: rows 0..63, cols 32..47 (in-bounds for interior)
        {
            int h = threadIdx.x;
            int r = h >> 2, d = 8 + (h & 3);
            const float* prow = pb + (size_t)(r0 + r) * WDIM + (c0 + d * 4);
            const float* trow = tb + (size_t)(r0 + r) * WDIM + (c0 + d * 4);
            float4 a4 = *(const float4*)prow;
            float4 b4 = *(const float4*)trow;
            float qp[4] = {quant_u8f(a4.x), quant_u8f(a4.y), quant_u8f(a4.z), quant_u8f(a4.w)};
            float qt[4] = {quant_u8f(b4.x), quant_u8f(b4.y), quant_u8f(b4.z), quant_u8f(b4.w)};
            *(uint2*)&Ip[r * IN_S + d * 4] = make_uint2(pk2(qp[0], qp[1]), pk2(qp[2], qp[3]));
            *(uint2*)&It[r * IN_S + d * 4] = make_uint2(pk2(qt[0], qt[1]), pk2(qt[2], qt[3]));
        }
        // halo 1: rows 64..79, all 12 dword-groups (192 items)
        if (threadIdx.x < 192) {
            int h = threadIdx.x;
            int rq = h / 12;
            int r = 64 + rq, d = h - rq * 12;
            const float* prow = pb + (size_t)(r0 + r) * WDIM + (c0 + d * 4);
            const float* trow = tb + (size_t)(r0 + r) * WDIM + (c0 + d * 4);
            float4 a4 = *(const float4*)prow;
            float4 b4 = *(const float4*)trow;
            float qp[4] = {quant_u8f(a4.x), quant_u8f(a4.y), quant_u8f(a4.z), quant_u8f(a4.w)};
            float qt[4] = {quant_u8f(b4.x), quant_u8f(b4.y), quant_u8f(b4.z), quant_u8f(b4.w)};
            *(uint2*)&Ip[r * IN_S + d * 4] = make_uint2(pk2(qp[0], qp[1]), pk2(qp[2], qp[3]));
            *(uint2*)&It[r * IN_S + d * 4] = make_uint2(pk2(qt[0], qt[1]), pk2(qt[2], qt[3]));
        }
    } else {
        // edge tiles: same enumeration, guarded (core pixels are always
        // in-bounds; only down-row, right-neighbor, and halo need guards)
#pragma unroll
        for (int i = 0; i < 2; ++i) {
            int item = threadIdx.x + i * 256;
            int r = item >> 3, d = item & 7;
            int gr = r0 + r, gc = c0 + d * 4;
            const float* prow = pb + (size_t)gr * WDIM + gc;
            const float* trow = tb + (size_t)gr * WDIM + gc;
            float4 a4 = *(const float4*)prow;
            float4 b4 = *(const float4*)trow;
            bool down = gr < (HDIM - 1);
            bool hasR = (gc + 4) < WDIM;
            float4 z4 = make_float4(0.f, 0.f, 0.f, 0.f);
            float4 ad = down ? *(const float4*)(prow + WDIM) : z4;
            float4 bd = down ? *(const float4*)(trow + WDIM) : z4;
            float p5 = hasR ? prow[4] : 0.0f;
            float t5 = hasR ? trow[4] : 0.0f;
            float pv[4] = {a4.x, a4.y, a4.z, a4.w};
            float tv[4] = {b4.x, b4.y, b4.z, b4.w};
            float pd[4] = {ad.x, ad.y, ad.z, ad.w};
            float td[4] = {bd.x, bd.y, bd.z, bd.w};
            float qp[4], qt[4];
#pragma unroll
            for (int k = 0; k < 4; ++k) { qp[k] = quant_u8f(pv[k]); qt[k] = quant_u8f(tv[k]); }
#pragma unroll
            for (int k = 0; k < 4; ++k) {
                float av = pv[k], bv = tv[k];
                float dd = av - bv;
                s[0] += fabsf(dd);
                s[3] += fmaxf(fabsf(av) - 1.0f, 0.0f);
                s[4] += av;  s[5] += bv;
                s[6] = fmaf(av, av, s[6]);
                s[7] = fmaf(bv, bv, s[7]);
                if (down) s[1] += fabsf(dd - (pd[k] - td[k]));
                float nr  = (k < 3) ? pv[k + 1] : p5;
                float nt2 = (k < 3) ? tv[k + 1] : t5;
                if (k < 3 || hasR) s[2] += fabsf(dd - (nr - nt2));
                float qd = qp[k] - qt[k];
                s[8] = fmaf(qd, qd, s[8]);
            }
            *(uint2*)&Ip[r * IN_S + d * 4] = make_uint2(pk2(qp[0], qp[1]), pk2(qp[2], qp[3]));
            *(uint2*)&It[r * IN_S + d * 4] = make_uint2(pk2(qt[0], qt[1]), pk2(qt[2], qt[3]));
        }
#pragma unroll
        for (int ph = 0; ph < 2; ++ph) {
            int r, d;
            bool active = true;
            if (ph == 0) { int h = threadIdx.x; r = h >> 2; d = 8 + (h & 3); }
            else {
                int h = threadIdx.x;
                active = h < 192;
                int rq = h / 12;
                r = 64 + rq; d = h - rq * 12;
            }
            if (active) {
                int gr = r0 + r, gc = c0 + d * 4;
                bool rowok = gr < HDIM;
                const float* prow = pb + (size_t)gr * WDIM + gc;
                const float* trow = tb + (size_t)gr * WDIM + gc;
                float qp[4], qt[4];
                if (rowok && (gc + 3) < WDIM) {
                    float4 a4 = *(const float4*)prow;
                    float4 b4 = *(const float4*)trow;
                    qp[0]=quant_u8f(a4.x); qp[1]=quant_u8f(a4.y); qp[2]=quant_u8f(a4.z); qp[3]=quant_u8f(a4.w);
                    qt[0]=quant_u8f(b4.x); qt[1]=quant_u8f(b4.y); qt[2]=quant_u8f(b4.z); qt[3]=quant_u8f(b4.w);
                } else {
#pragma unroll
                    for (int k = 0; k < 4; ++k) {
                        bool ok = rowok && (gc + k) < WDIM;
                        qp[k] = ok ? quant_u8f(prow[k]) : 0.0f;
                        qt[k] = ok ? quant_u8f(trow[k]) : 0.0f;
                    }
                }
                *(uint2*)&Ip[r * IN_S + d * 4] = make_uint2(pk2(qp[0], qp[1]), pk2(qp[2], qp[3]));
                *(uint2*)&It[r * IN_S + d * 4] = make_uint2(pk2(qt[0], qt[1]), pk2(qt[2], qt[3]));
            }
        }
    }
    __syncthreads();

    const int lane = threadIdx.x & 63;
    const int wid  = threadIdx.x >> 6;
    const int q    = lane >> 4;
    const int ml   = lane & 15;
    // shared Gaussian fragment: horizontal B-operand == vertical A-operand
    const half8 gfrag = *(const half8*)&Tg[ml * 32 + q * 8];
    const f32x4 zero4 = {0.f, 0.f, 0.f, 0.f};

    // ---- stage H: horizontal conv via MFMA, 10 positions over 4 waves ----
    for (int pos = wid; pos < 10; pos += 4) {
        int rb = (pos >> 1) * 16;
        int cb = pos & 1;
        const half8 ap = *(const half8*)&Ip[(rb + ml) * IN_S + cb * 16 + q * 8];
        const half8 at = *(const half8*)&It[(rb + ml) * IN_S + cb * 16 + q * 8];
        f32x4 d0 = __builtin_amdgcn_mfma_f32_16x16x32_f16(ap,      gfrag, zero4, 0, 0, 0);
        f32x4 d1 = __builtin_amdgcn_mfma_f32_16x16x32_f16(at,      gfrag, zero4, 0, 0, 0);
        f32x4 d2 = __builtin_amdgcn_mfma_f32_16x16x32_f16(ap * ap, gfrag, zero4, 0, 0, 0);
        f32x4 d3 = __builtin_amdgcn_mfma_f32_16x16x32_f16(at * at, gfrag, zero4, 0, 0, 0);
        f32x4 d4 = __builtin_amdgcn_mfma_f32_16x16x32_f16(ap * at, gfrag, zero4, 0, 0, 0);
        int hb = (cb * 16 + ml) * HT_S + rb + q * 4;  // transposed write: rows contiguous
        *(uint2*)&HT[0][hb] = make_uint2(pk2(d0[0], d0[1]), pk2(d0[2], d0[3]));
        *(uint2*)&HT[1][hb] = make_uint2(pk2(d1[0], d1[1]), pk2(d1[2], d1[3]));
        *(uint2*)&HT[2][hb] = make_uint2(pk2(d2[0], d2[1]), pk2(d2[2], d2[3]));
        *(uint2*)&HT[3][hb] = make_uint2(pk2(d3[0], d3[1]), pk2(d3[2], d3[3]));
        *(uint2*)&HT[4][hb] = make_uint2(pk2(d4[0], d4[1]), pk2(d4[2], d4[3]));
    }
    __syncthreads();

    // ---- stage V: vertical conv via MFMA + SSIM map; 8 positions, 2/wave ----
    float ssum = 0.0f;
    const int th_ = min(TH, OUTW - r0);
    const int tw_ = min(TW, OUTW - c0);
    for (int vp = wid; vp < 8; vp += 4) {
        int rb2 = (vp >> 1) * 16;
        int cb2 = vp & 1;
        f32x4 acc[5];
#pragma unroll
        for (int arr = 0; arr < 5; ++arr) {
            const half8 bf = *(const half8*)&HT[arr][(cb2 * 16 + ml) * HT_S + rb2 + q * 8];
            acc[arr] = __builtin_amdgcn_mfma_f32_16x16x32_f16(gfrag, bf, zero4, 0, 0, 0);
        }
        int col = cb2 * 16 + ml;
#pragma unroll
        for (int reg = 0; reg < 4; ++reg) {
            int row = rb2 + q * 4 + reg;
            if (interior || (row < th_ && col < tw_)) {
                float mu1 = acc[0][reg], mu2 = acc[1][reg];
                float vpp = acc[2][reg], vtt = acc[3][reg], vpt = acc[4][reg];
                float mu1s = mu1 * mu1, mu2s = mu2 * mu2, mu12 = mu1 * mu2;
                float sg1 = vpp - mu1s, sg2 = vtt - mu2s, sg12 = vpt - mu12;
                float num = (2.0f * mu12 + C1F) * (2.0f * sg12 + C2F);
                float den = (mu1s + mu2s + C1F) * (sg1 + sg2 + C2F);
                ssum += num * __builtin_amdgcn_rcpf(den);
            }
        }
    }

    // ---- block reduction of 10 partials; per-block stores ----
    float st10[10];
#pragma unroll
    for (int c = 0; c < 9; ++c) st10[c] = s[c];
    st10[9] = ssum;
#pragma unroll
    for (int c = 0; c < 10; ++c) {
        float v = st10[c];
        for (int off = 32; off > 0; off >>= 1) v += __shfl_down(v, off);
        st10[c] = v;
    }
    if (lane == 0) {
#pragma unroll
        for (int c = 0; c < 10; ++c) sred[wid][c] = st10[c];
    }
    __syncthreads();
    if (threadIdx.x < 10) {
        int c = threadIdx.x;
        int bid = ((b * 32) + blockIdx.y) * 64 + blockIdx.x;
        pr[c * NBLK + bid] = sred[0][c] + sred[1][c] + sred[2][c] + sred[3][c];
    }
}

// ---------------------------------------------------------------------------
// Final: ONE block. 40 segments of 2048 contiguous floats, coalesced float4
// reads, f64 shfl-reduce; thread 0 does the scalar combine.
// ---------------------------------------------------------------------------
__global__ __launch_bounds__(256) void amsr2_final(
        const float* __restrict__ pr, float* __restrict__ out)
{
    __shared__ double seg[40];
    int wid = threadIdx.x >> 6, lane = threadIdx.x & 63;
    for (int sidx = wid; sidx < 40; sidx += 4) {
        int c = sidx >> 2, b = sidx & 3;
        const float* base = pr + c * NBLK + b * 2048;
        float4 v[8];
#pragma unroll
        for (int it = 0; it < 8; ++it)
            v[it] = *(const float4*)(base + (it * 64 + lane) * 4);
        double acc = 0.0;
#pragma unroll
        for (int it = 0; it < 8; ++it)
            acc += (double)v[it].x + (double)v[it].y + (double)v[it].z + (double)v[it].w;
        for (int off = 32; off > 0; off >>= 1) acc += __shfl_down(acc, off);
        if (lane == 0) seg[sidx] = acc;
    }
    __syncthreads();
    if (threadIdx.x != 0) return;
    const double n = (double)NPIX;
    double sum0 = 0, sum1 = 0, sum2 = 0, sum3 = 0;
    for (int b = 0; b < 4; ++b) {
        sum0 += seg[0*4+b]; sum1 += seg[1*4+b]; sum2 += seg[2*4+b]; sum3 += seg[3*4+b];
    }
    double l1   = sum0 / (4.0 * n);
    double grad = sum1 / (4.0 * 2047.0 * 2048.0) + sum2 / (4.0 * 2048.0 * 2047.0);
    double energy = 0.0, dist = 0.0, psnr_sum = 0.0, ssim_sum = 0.0;
    for (int b = 0; b < 4; ++b) {
        double Sp  = seg[4*4+b],  St  = seg[5*4+b];
        double Spp = seg[6*4+b],  Stt = seg[7*4+b];
        double Su8 = seg[8*4+b],  Sss = seg[9*4+b];
        double pm = Sp / n, tm = St / n;
        double dm = pm - tm; energy += dm * dm;
        double vp = (Spp - n * pm * pm) / (n - 1.0);
        double vt = (Stt - n * tm * tm) / (n - 1.0);
        double ps = sqrt(fmax(vp, 0.0)), ts = sqrt(fmax(vt, 0.0));
        double dd = ps - ts; dist += dd * dd;
        double mse = Su8 / n;
        double psnr = (mse == 0.0) ? 100.0 : 10.0 * log10(65025.0 / fmax(mse, 1e-12));
        psnr_sum += psnr;
        ssim_sum += Sss / ((double)OUTW * (double)OUTW);
    }
    energy *= 0.25; dist *= 0.25;
    double range_pen = sum3 / (4.0 * n);
    double phys = energy + 0.5 * dist + 0.1 * range_pen;
    double ssim_mean = fmin(fmax(ssim_sum * 0.25, 0.0), 1.0);
    double total = l1 + 0.15 * grad + 0.05 * phys + 0.1 * (1.0 - ssim_mean);
    out[0] = (float)total;
    out[1] = (float)(psnr_sum * 0.25);
    out[2] = (float)ssim_mean;
}

extern "C" void kernel_launch(void* const* d_in, const int* in_sizes, int n_in,
                              void* d_out, int out_size, void* d_ws, size_t ws_size,
                              hipStream_t stream)
{
    (void)in_sizes; (void)n_in; (void)out_size; (void)ws_size;
    const float* pred = (const float*)d_in[0];
    const float* targ = (const float*)d_in[1];
    float* out = (float*)d_out;
    float* pr  = (float*)d_ws;            // 10 * 8192 floats of per-block partials

    GaussW gw;                            // host-side f64 Gaussian, cast to f32
    {
        double e[11], sm = 0.0;
        for (int i = 0; i < 11; ++i) {
            double d = (double)(i - 5);
            e[i] = exp(-(d * d) / 4.5);
            sm += e[i];
        }
        for (int i = 0; i < 11; ++i) gw.g[i] = (float)(e[i] / sm);
    }

    amsr2_fused<<<dim3(64, 32, 4), 256, 0, stream>>>(pred, targ, pr, gw);
    amsr2_final<<<1, 256, 0, stream>>>(pr, out);
}

// Round 8
// 183.431 us; speedup vs baseline: 4.5552x; 1.0442x over previous
//
#include <hip/hip_runtime.h>
#include <math.h>

#define HDIM 2048
#define WDIM 2048
#define NPIX (HDIM*WDIM)
#define OUTW 2038          /* valid conv output size: 2048-10 */

#define C1F 6.5025f        /* (0.01*255)^2 */
#define C2F 58.5225f       /* (0.03*255)^2 */

constexpr int TH   = 64, TW = 32;  // output tile
constexpr int IN_R = 80;           // input rows staged (5 MFMA row-blocks of 16)
constexpr int IN8S = 18;           // u8 input row stride in DWORDS (72 B; odd-ish banks)
constexpr int HT_S = 88;           // H_T stride along r in f16 (176 B; 2-way banks, b128-aligned)
constexpr int NBLK = 8192;         // 64 x 32 x 4 blocks

struct GaussW { float g[11]; };

typedef _Float16 half8 __attribute__((ext_vector_type(8)));
typedef float    f32x4 __attribute__((ext_vector_type(4)));

// quant: bit-exact vs reference sequence. (clip(x)+1)*0.5 then *255 ==
// (clip(x)+1)*127.5 (the *0.5 is exact); trunc == floor for v >= 0.
__device__ __forceinline__ float quant_u8f(float x) {
    float c = __builtin_amdgcn_fmed3f(x, -1.0f, 1.0f);
    return truncf((c + 1.0f) * 127.5f);
}
// halo variant: cvt_pk_u8_f32 truncates+clamps on pack, so skip truncf
__device__ __forceinline__ float quant_h(float x) {
    float c = __builtin_amdgcn_fmed3f(x, -1.0f, 1.0f);
    return (c + 1.0f) * 127.5f;
}

__device__ __forceinline__ unsigned pk2(float a, float b) {
    return __builtin_bit_cast(unsigned, __builtin_amdgcn_cvt_pkrtz(a, b));
}

__device__ __forceinline__ unsigned pack4_u8(const float* v) {
#if __has_builtin(__builtin_amdgcn_cvt_pk_u8_f32)
    unsigned r = 0;
    r = __builtin_amdgcn_cvt_pk_u8_f32(v[0], 0, r);
    r = __builtin_amdgcn_cvt_pk_u8_f32(v[1], 1, r);
    r = __builtin_amdgcn_cvt_pk_u8_f32(v[2], 2, r);
    r = __builtin_amdgcn_cvt_pk_u8_f32(v[3], 3, r);
    return r;
#else
    return ((unsigned)(int)v[0]) | (((unsigned)(int)v[1]) << 8) |
           (((unsigned)(int)v[2]) << 16) | (((unsigned)(int)v[3]) << 24);
#endif
}

// 8 packed u8 (2 dwords, little-endian col order) -> half8 (exact)
__device__ __forceinline__ half8 unpack_u8x8(unsigned lo, unsigned hi) {
    union { unsigned u[4]; half8 h; } r;
    r.u[0] = pk2((float)(lo & 0xffu),         (float)((lo >> 8)  & 0xffu));
    r.u[1] = pk2((float)((lo >> 16) & 0xffu), (float)((lo >> 24) & 0xffu));
    r.u[2] = pk2((float)(hi & 0xffu),         (float)((hi >> 8)  & 0xffu));
    r.u[3] = pk2((float)((hi >> 16) & 0xffu), (float)((hi >> 24) & 0xffu));
    return r.h;
}

// ---------------------------------------------------------------------------
// Fused kernel, MFMA edition (round 8: u8 LDS staging -> 40 KB -> 4 blocks/CU).
//   stage A: load f32, pointwise stats on owned core, quantize -> u8x4 LDS
//   stage H: horizontal 11-tap conv as mfma_f32_16x16x32_f16 (A = unpacked
//            data rows, B = banded Gaussian T); D written transposed to H_T.
//   stage V: vertical 11-tap conv as MFMA (A = same T fragment, B = H_T b128)
//            + SSIM map on aligned C/D fragments.
// Channels: 0:l1 1:gxH 2:gyW 3:relu 4:sp 5:st 6:spp 7:stt 8:su8 9:ssim
// ---------------------------------------------------------------------------
__global__ __launch_bounds__(256) void amsr2_fused(
        const float* __restrict__ pred, const float* __restrict__ targ,
        float* __restrict__ pr, GaussW gw)
{
    __shared__ unsigned Ip8[IN_R * IN8S];
    __shared__ unsigned It8[IN_R * IN8S];
    __shared__ alignas(16) _Float16 HT[5][32 * HT_S];
    __shared__ alignas(16) _Float16 Tg[16 * 32];      // T[n][k] = g[k-n]
    __shared__ float sred[4][10];

    const int b  = blockIdx.z;
    const int r0 = blockIdx.y * TH;
    const int c0 = blockIdx.x * TW;
    const float* pb = pred + (size_t)b * NPIX;
    const float* tb = targ + (size_t)b * NPIX;
    const bool interior = (blockIdx.y < 31) && (blockIdx.x < 63);

    // ---- banded Gaussian table (threads 0..15; each owns its row) ----
    if (threadIdx.x < 16) {
        int n = threadIdx.x;
#pragma unroll
        for (int i = 0; i < 16; ++i) ((unsigned*)Tg)[n * 16 + i] = 0u;
#pragma unroll
        for (int j = 0; j < 11; ++j) Tg[n * 32 + n + j] = (_Float16)gw.g[j];
    }

    float s[9];
#pragma unroll
    for (int c = 0; c < 9; ++c) s[c] = 0.0f;

    // ---- stage A: 80 rows x 48 cols staged; core(512) + halo(256+192) ----
    if (interior) {
        // core items: 64 rows x 8 dword-groups (cols 0..31) -- fully unguarded
#pragma unroll
        for (int i = 0; i < 2; ++i) {
            int item = threadIdx.x + i * 256;
            int r = item >> 3, d = item & 7;
            const float* prow = pb + (size_t)(r0 + r) * WDIM + (c0 + d * 4);
            const float* trow = tb + (size_t)(r0 + r) * WDIM + (c0 + d * 4);
            float4 a4 = *(const float4*)prow;
            float4 b4 = *(const float4*)trow;
            float4 ad = *(const float4*)(prow + WDIM);
            float4 bd = *(const float4*)(trow + WDIM);
            float p5 = prow[4], t5 = trow[4];
            float pv[4] = {a4.x, a4.y, a4.z, a4.w};
            float tv[4] = {b4.x, b4.y, b4.z, b4.w};
            float pd[4] = {ad.x, ad.y, ad.z, ad.w};
            float td[4] = {bd.x, bd.y, bd.z, bd.w};
            float qp[4], qt[4];
#pragma unroll
            for (int k = 0; k < 4; ++k) { qp[k] = quant_u8f(pv[k]); qt[k] = quant_u8f(tv[k]); }
#pragma unroll
            for (int k = 0; k < 4; ++k) {
                float av = pv[k], bv = tv[k];
                float dd = av - bv;
                s[0] += fabsf(dd);
                s[3] += fmaxf(fabsf(av) - 1.0f, 0.0f);
                s[4] += av;  s[5] += bv;
                s[6] = fmaf(av, av, s[6]);
                s[7] = fmaf(bv, bv, s[7]);
                s[1] += fabsf(dd - (pd[k] - td[k]));
                float nr  = (k < 3) ? pv[k + 1] : p5;
                float nt2 = (k < 3) ? tv[k + 1] : t5;
                s[2] += fabsf(dd - (nr - nt2));
                float qd = qp[k] - qt[k];
                s[8] = fmaf(qd, qd, s[8]);
            }
            Ip8[r * IN8S + d] = pack4_u8(qp);
            It8[r * IN8S + d] = pack4_u8(qt);
        }
        // halo 0: rows 0..63, cols 32..47 (in-bounds for interior)
        {
            int h = threadIdx.x;
            int r = h >> 2, d = 8 + (h & 3);
            const float* prow = pb + (size_t)(r0 + r) * WDIM + (c0 + d * 4);
            const float* trow = tb + (size_t)(r0 + r) * WDIM + (c0 + d * 4);
            float4 a4 = *(const float4*)prow;
            float4 b4 = *(const float4*)trow;
            float qp[4] = {quant_h(a4.x), quant_h(a4.y), quant_h(a4.z), quant_h(a4.w)};
            float qt[4] = {quant_h(b4.x), quant_h(b4.y), quant_h(b4.z), quant_h(b4.w)};
            Ip8[r * IN8S + d] = pack4_u8(qp);
            It8[r * IN8S + d] = pack4_u8(qt);
        }
        // halo 1: rows 64..79, all 12 dword-groups (192 items)
        if (threadIdx.x < 192) {
            int h = threadIdx.x;
            int rq = h / 12;
            int r = 64 + rq, d = h - rq * 12;
            const float* prow = pb + (size_t)(r0 + r) * WDIM + (c0 + d * 4);
            const float* trow = tb + (size_t)(r0 + r) * WDIM + (c0 + d * 4);
            float4 a4 = *(const float4*)prow;
            float4 b4 = *(const float4*)trow;
            float qp[4] = {quant_h(a4.x), quant_h(a4.y), quant_h(a4.z), quant_h(a4.w)};
            float qt[4] = {quant_h(b4.x), quant_h(b4.y), quant_h(b4.z), quant_h(b4.w)};
            Ip8[r * IN8S + d] = pack4_u8(qp);
            It8[r * IN8S + d] = pack4_u8(qt);
        }
    } else {
        // edge tiles: same enumeration, guarded (core pixels always in-bounds;
        // only down-row, right-neighbor, and halo need guards)
#pragma unroll
        for (int i = 0; i < 2; ++i) {
            int item = threadIdx.x + i * 256;
            int r = item >> 3, d = item & 7;
            int gr = r0 + r, gc = c0 + d * 4;
            const float* prow = pb + (size_t)gr * WDIM + gc;
            const float* trow = tb + (size_t)gr * WDIM + gc;
            float4 a4 = *(const float4*)prow;
            float4 b4 = *(const float4*)trow;
            bool down = gr < (HDIM - 1);
            bool hasR = (gc + 4) < WDIM;
            float4 z4 = make_float4(0.f, 0.f, 0.f, 0.f);
            float4 ad = down ? *(const float4*)(prow + WDIM) : z4;
            float4 bd = down ? *(const float4*)(trow + WDIM) : z4;
            float p5 = hasR ? prow[4] : 0.0f;
            float t5 = hasR ? trow[4] : 0.0f;
            float pv[4] = {a4.x, a4.y, a4.z, a4.w};
            float tv[4] = {b4.x, b4.y, b4.z, b4.w};
            float pd[4] = {ad.x, ad.y, ad.z, ad.w};
            float td[4] = {bd.x, bd.y, bd.z, bd.w};
            float qp[4], qt[4];
#pragma unroll
            for (int k = 0; k < 4; ++k) { qp[k] = quant_u8f(pv[k]); qt[k] = quant_u8f(tv[k]); }
#pragma unroll
            for (int k = 0; k < 4; ++k) {
                float av = pv[k], bv = tv[k];
                float dd = av - bv;
                s[0] += fabsf(dd);
                s[3] += fmaxf(fabsf(av) - 1.0f, 0.0f);
                s[4] += av;  s[5] += bv;
                s[6] = fmaf(av, av, s[6]);
                s[7] = fmaf(bv, bv, s[7]);
                if (down) s[1] += fabsf(dd - (pd[k] - td[k]));
                float nr  = (k < 3) ? pv[k + 1] : p5;
                float nt2 = (k < 3) ? tv[k + 1] : t5;
                if (k < 3 || hasR) s[2] += fabsf(dd - (nr - nt2));
                float qd = qp[k] - qt[k];
                s[8] = fmaf(qd, qd, s[8]);
            }
            Ip8[r * IN8S + d] = pack4_u8(qp);
            It8[r * IN8S + d] = pack4_u8(qt);
        }
#pragma unroll
        for (int ph = 0; ph < 2; ++ph) {
            int r, d;
            bool active = true;
            if (ph == 0) { int h = threadIdx.x; r = h >> 2; d = 8 + (h & 3); }
            else {
                int h = threadIdx.x;
                active = h < 192;
                int rq = h / 12;
                r = 64 + rq; d = h - rq * 12;
            }
            if (active) {
                int gr = r0 + r, gc = c0 + d * 4;
                bool rowok = gr < HDIM;
                const float* prow = pb + (size_t)gr * WDIM + gc;
                const float* trow = tb + (size_t)gr * WDIM + gc;
                float qp[4], qt[4];
                if (rowok && (gc + 3) < WDIM) {
                    float4 a4 = *(const float4*)prow;
                    float4 b4 = *(const float4*)trow;
                    qp[0]=quant_h(a4.x); qp[1]=quant_h(a4.y); qp[2]=quant_h(a4.z); qp[3]=quant_h(a4.w);
                    qt[0]=quant_h(b4.x); qt[1]=quant_h(b4.y); qt[2]=quant_h(b4.z); qt[3]=quant_h(b4.w);
                } else {
#pragma unroll
                    for (int k = 0; k < 4; ++k) {
                        bool ok = rowok && (gc + k) < WDIM;
                        qp[k] = ok ? quant_h(prow[k]) : 0.0f;
                        qt[k] = ok ? quant_h(trow[k]) : 0.0f;
                    }
                }
                Ip8[r * IN8S + d] = pack4_u8(qp);
                It8[r * IN8S + d] = pack4_u8(qt);
            }
        }
    }
    __syncthreads();

    const int lane = threadIdx.x & 63;
    const int wid  = threadIdx.x >> 6;
    const int q    = lane >> 4;
    const int ml   = lane & 15;
    // shared Gaussian fragment: horizontal B-operand == vertical A-operand
    const half8 gfrag = *(const half8*)&Tg[ml * 32 + q * 8];
    const f32x4 zero4 = {0.f, 0.f, 0.f, 0.f};

    // ---- stage H: horizontal conv via MFMA, 10 positions over 4 waves ----
    for (int pos = wid; pos < 10; pos += 4) {
        int rb = (pos >> 1) * 16;
        int cb = pos & 1;
        int base = (rb + ml) * IN8S + cb * 4 + q * 2;
        unsigned plo = Ip8[base], phi = Ip8[base + 1];
        unsigned tlo = It8[base], thi = It8[base + 1];
        const half8 ap = unpack_u8x8(plo, phi);
        const half8 at = unpack_u8x8(tlo, thi);
        f32x4 d0 = __builtin_amdgcn_mfma_f32_16x16x32_f16(ap,      gfrag, zero4, 0, 0, 0);
        f32x4 d1 = __builtin_amdgcn_mfma_f32_16x16x32_f16(at,      gfrag, zero4, 0, 0, 0);
        f32x4 d2 = __builtin_amdgcn_mfma_f32_16x16x32_f16(ap * ap, gfrag, zero4, 0, 0, 0);
        f32x4 d3 = __builtin_amdgcn_mfma_f32_16x16x32_f16(at * at, gfrag, zero4, 0, 0, 0);
        f32x4 d4 = __builtin_amdgcn_mfma_f32_16x16x32_f16(ap * at, gfrag, zero4, 0, 0, 0);
        int hb = (cb * 16 + ml) * HT_S + rb + q * 4;  // transposed write: rows contiguous
        *(uint2*)&HT[0][hb] = make_uint2(pk2(d0[0], d0[1]), pk2(d0[2], d0[3]));
        *(uint2*)&HT[1][hb] = make_uint2(pk2(d1[0], d1[1]), pk2(d1[2], d1[3]));
        *(uint2*)&HT[2][hb] = make_uint2(pk2(d2[0], d2[1]), pk2(d2[2], d2[3]));
        *(uint2*)&HT[3][hb] = make_uint2(pk2(d3[0], d3[1]), pk2(d3[2], d3[3]));
        *(uint2*)&HT[4][hb] = make_uint2(pk2(d4[0], d4[1]), pk2(d4[2], d4[3]));
    }
    __syncthreads();

    // ---- stage V: vertical conv via MFMA + SSIM map; 8 positions, 2/wave ----
    float ssum = 0.0f;
    const int th_ = min(TH, OUTW - r0);
    const int tw_ = min(TW, OUTW - c0);
    for (int vp = wid; vp < 8; vp += 4) {
        int rb2 = (vp >> 1) * 16;
        int cb2 = vp & 1;
        f32x4 acc[5];
#pragma unroll
        for (int arr = 0; arr < 5; ++arr) {
            const half8 bf = *(const half8*)&HT[arr][(cb2 * 16 + ml) * HT_S + rb2 + q * 8];
            acc[arr] = __builtin_amdgcn_mfma_f32_16x16x32_f16(gfrag, bf, zero4, 0, 0, 0);
        }
        int col = cb2 * 16 + ml;
#pragma unroll
        for (int reg = 0; reg < 4; ++reg) {
            int row = rb2 + q * 4 + reg;
            if (interior || (row < th_ && col < tw_)) {
                float mu1 = acc[0][reg], mu2 = acc[1][reg];
                float vpp = acc[2][reg], vtt = acc[3][reg], vpt = acc[4][reg];
                float mu1s = mu1 * mu1, mu2s = mu2 * mu2, mu12 = mu1 * mu2;
                float sg1 = vpp - mu1s, sg2 = vtt - mu2s, sg12 = vpt - mu12;
                float num = (2.0f * mu12 + C1F) * (2.0f * sg12 + C2F);
                float den = (mu1s + mu2s + C1F) * (sg1 + sg2 + C2F);
                ssum += num * __builtin_amdgcn_rcpf(den);
            }
        }
    }

    // ---- block reduction of 10 partials; per-block stores ----
    float st10[10];
#pragma unroll
    for (int c = 0; c < 9; ++c) st10[c] = s[c];
    st10[9] = ssum;
#pragma unroll
    for (int c = 0; c < 10; ++c) {
        float v = st10[c];
        for (int off = 32; off > 0; off >>= 1) v += __shfl_down(v, off);
        st10[c] = v;
    }
    if (lane == 0) {
#pragma unroll
        for (int c = 0; c < 10; ++c) sred[wid][c] = st10[c];
    }
    __syncthreads();
    if (threadIdx.x < 10) {
        int c = threadIdx.x;
        int bid = ((b * 32) + blockIdx.y) * 64 + blockIdx.x;
        pr[c * NBLK + bid] = sred[0][c] + sred[1][c] + sred[2][c] + sred[3][c];
    }
}

// ---------------------------------------------------------------------------
// Final: ONE block. 40 segments of 2048 contiguous floats, coalesced float4
// reads, f64 shfl-reduce; thread 0 does the scalar combine.
// ---------------------------------------------------------------------------
__global__ __launch_bounds__(256) void amsr2_final(
        const float* __restrict__ pr, float* __restrict__ out)
{
    __shared__ double seg[40];
    int wid = threadIdx.x >> 6, lane = threadIdx.x & 63;
    for (int sidx = wid; sidx < 40; sidx += 4) {
        int c = sidx >> 2, b = sidx & 3;
        const float* base = pr + c * NBLK + b * 2048;
        float4 v[8];
#pragma unroll
        for (int it = 0; it < 8; ++it)
            v[it] = *(const float4*)(base + (it * 64 + lane) * 4);
        double acc = 0.0;
#pragma unroll
        for (int it = 0; it < 8; ++it)
            acc += (double)v[it].x + (double)v[it].y + (double)v[it].z + (double)v[it].w;
        for (int off = 32; off > 0; off >>= 1) acc += __shfl_down(acc, off);
        if (lane == 0) seg[sidx] = acc;
    }
    __syncthreads();
    if (threadIdx.x != 0) return;
    const double n = (double)NPIX;
    double sum0 = 0, sum1 = 0, sum2 = 0, sum3 = 0;
    for (int b = 0; b < 4; ++b) {
        sum0 += seg[0*4+b]; sum1 += seg[1*4+b]; sum2 += seg[2*4+b]; sum3 += seg[3*4+b];
    }
    double l1   = sum0 / (4.0 * n);
    double grad = sum1 / (4.0 * 2047.0 * 2048.0) + sum2 / (4.0 * 2048.0 * 2047.0);
    double energy = 0.0, dist = 0.0, psnr_sum = 0.0, ssim_sum = 0.0;
    for (int b = 0; b < 4; ++b) {
        double Sp  = seg[4*4+b],  St  = seg[5*4+b];
        double Spp = seg[6*4+b],  Stt = seg[7*4+b];
        double Su8 = seg[8*4+b],  Sss = seg[9*4+b];
        double pm = Sp / n, tm = St / n;
        double dm = pm - tm; energy += dm * dm;
        double vp = (Spp - n * pm * pm) / (n - 1.0);
        double vt = (Stt - n * tm * tm) / (n - 1.0);
        double ps = sqrt(fmax(vp, 0.0)), ts = sqrt(fmax(vt, 0.0));
        double dd = ps - ts; dist += dd * dd;
        double mse = Su8 / n;
        double psnr = (mse == 0.0) ? 100.0 : 10.0 * log10(65025.0 / fmax(mse, 1e-12));
        psnr_sum += psnr;
        ssim_sum += Sss / ((double)OUTW * (double)OUTW);
    }
    energy *= 0.25; dist *= 0.25;
    double range_pen = sum3 / (4.0 * n);
    double phys = energy + 0.5 * dist + 0.1 * range_pen;
    double ssim_mean = fmin(fmax(ssim_sum * 0.25, 0.0), 1.0);
    double total = l1 + 0.15 * grad + 0.05 * phys + 0.1 * (1.0 - ssim_mean);
    out[0] = (float)total;
    out[1] = (float)(psnr_sum * 0.25);
    out[2] = (float)ssim_mean;
}

extern "C" void kernel_launch(void* const* d_in, const int* in_sizes, int n_in,
                              void* d_out, int out_size, void* d_ws, size_t ws_size,
                              hipStream_t stream)
{
    (void)in_sizes; (void)n_in; (void)out_size; (void)ws_size;
    const float* pred = (const float*)d_in[0];
    const float* targ = (const float*)d_in[1];
    float* out = (float*)d_out;
    float* pr  = (float*)d_ws;            // 10 * 8192 floats of per-block partials

    GaussW gw;                            // host-side f64 Gaussian, cast to f32
    {
        double e[11], sm = 0.0;
        for (int i = 0; i < 11; ++i) {
            double d = (double)(i - 5);
            e[i] = exp(-(d * d) / 4.5);
            sm += e[i];
        }
        for (int i = 0; i < 11; ++i) gw.g[i] = (float)(e[i] / sm);
    }

    amsr2_fused<<<dim3(64, 32, 4), 256, 0, stream>>>(pred, targ, pr, gw);
    amsr2_final<<<1, 256, 0, stream>>>(pr, out);
}